// Round 2
// baseline (447.252 us; speedup 1.0000x reference)
//
#include <hip/hip_runtime.h>
#include <stdint.h>

#define DI __device__ __forceinline__

typedef unsigned short u16;
typedef unsigned int   u32;
typedef __attribute__((ext_vector_type(8))) short short8;
typedef __attribute__((ext_vector_type(4))) float f32x4;
typedef __attribute__((ext_vector_type(4))) u32   u32x4;

// ---- constants (problem shape hardcoded) ----
// B=2, S=2048, HID=2048, HQ=16, HKV=8, D=128

DI u16 f2bf(float f) {
    u32 u = __float_as_uint(f);
    u32 r = u + 0x7fff + ((u >> 16) & 1);   // RNE
    return (u16)(r >> 16);
}
DI float bf2f(u16 h) { return __uint_as_float(((u32)h) << 16); }

DI f32x4 mfma16(short8 a, short8 b, f32x4 c) {
    return __builtin_amdgcn_mfma_f32_16x16x32_bf16(a, b, c, 0, 0, 0);
}

DI void gload_lds16(const void* g, void* l) {
    __builtin_amdgcn_global_load_lds(
        (const __attribute__((address_space(1))) void*)g,
        (__attribute__((address_space(3))) void*)l, 16, 0, 0);
}

// ---------------- convert x f32 -> bf16 ----------------
__global__ __launch_bounds__(256) void cvt_x(const float* __restrict__ x,
                                             u16* __restrict__ o, int n4) {
    int i = blockIdx.x * 256 + threadIdx.x;
    if (i >= n4) return;
    float4 v = *(const float4*)(x + (size_t)i * 4);
    u32 p0 = (u32)f2bf(v.x) | ((u32)f2bf(v.y) << 16);
    u32 p1 = (u32)f2bf(v.z) | ((u32)f2bf(v.w) << 16);
    uint2 p; p.x = p0; p.y = p1;
    *(uint2*)(o + (size_t)i * 4) = p;
}

// ---------------- W [K][N] f32 -> WT [N][K] bf16 ----------------
__global__ __launch_bounds__(256) void transpose_cvt(const float* __restrict__ W,
                                                     u16* __restrict__ WT,
                                                     int K, int N) {
    __shared__ u16 tl[64][65];
    int tx = threadIdx.x & 15, ty = threadIdx.x >> 4;
    int tc = blockIdx.x * 64, tr = blockIdx.y * 64;
#pragma unroll
    for (int i = 0; i < 4; i++) {
        int r = tr + ty + i * 16;
        float4 v = *(const float4*)&W[(size_t)r * N + tc + tx * 4];
        tl[tx*4+0][ty+i*16] = f2bf(v.x);
        tl[tx*4+1][ty+i*16] = f2bf(v.y);
        tl[tx*4+2][ty+i*16] = f2bf(v.z);
        tl[tx*4+3][ty+i*16] = f2bf(v.w);
    }
    __syncthreads();
#pragma unroll
    for (int i = 0; i < 4; i++) {
        int n = tc + ty + i * 16;
        uint2 p;
        p.x = (u32)tl[ty+i*16][tx*4+0] | ((u32)tl[ty+i*16][tx*4+1] << 16);
        p.y = (u32)tl[ty+i*16][tx*4+2] | ((u32)tl[ty+i*16][tx*4+3] << 16);
        *(uint2*)&WT[(size_t)n * K + tr + tx * 4] = p;
    }
}

// ---------------- RoPE in-place on bf16 [tok][H*128], output scaled ----------------
__global__ __launch_bounds__(256) void rope_kernel(u16* __restrict__ buf,
                                                   const float* __restrict__ fc,
                                                   const float* __restrict__ fs,
                                                   int H, int tokshift, int total,
                                                   float oscale) {
    int idx = blockIdx.x * 256 + threadIdx.x;
    if (idx >= total) return;
    int tok = idx >> tokshift;
    int rem = idx & ((1 << tokshift) - 1);
    int h = rem >> 6, j = rem & 63;
    int s = tok & 2047;
    size_t a = ((size_t)tok * H + h) * 128 + 2 * j;
    u32 v = *(u32*)(buf + a);
    float re = bf2f((u16)(v & 0xffff));
    float im = bf2f((u16)(v >> 16));
    float c = fc[s * 64 + j], sn = fs[s * 64 + j];
    u32 o = (u32)f2bf((re * c - im * sn) * oscale) |
            ((u32)f2bf((re * sn + im * c) * oscale) << 16);
    *(u32*)(buf + a) = o;
}

// ---------------- fused QKV GEMM: A[4096][2048] * WqkvT[4096][2048] ----------------
// n < 2048 -> Q [tok][2048]; 2048..3072 -> K [tok][1024]; 3072..4096 -> V^T scatter
__global__ __launch_bounds__(256) void gemm_qkv(const u16* __restrict__ A,
                                                const u16* __restrict__ BT,
                                                u16* __restrict__ Qo,
                                                u16* __restrict__ Ko,
                                                u16* __restrict__ Vo) {
    __shared__ u16 As[128 * 32];
    __shared__ u16 Bs[128 * 32];
    const int tid = threadIdx.x;
    const int w = tid >> 6, l = tid & 63;
    const int m0 = blockIdx.y * 128, n0 = blockIdx.x * 128;
    const int wr = w >> 1, wc = w & 1;
    const int l15 = l & 15, lh = l >> 4;

    const f32x4 fz = {0.f, 0.f, 0.f, 0.f};
    f32x4 acc[4][4];
#pragma unroll
    for (int m = 0; m < 4; m++)
#pragma unroll
        for (int n = 0; n < 4; n++) acc[m][n] = fz;

    const int rowA = w * 32 + (l >> 2);
    const int colb = (l & 3) * 8;

    for (int k0 = 0; k0 < 2048; k0 += 32) {
        __syncthreads();
#pragma unroll
        for (int c = 0; c < 2; c++) {
            gload_lds16(A  + (size_t)(m0 + rowA + c * 16) * 2048 + k0 + colb,
                        &As[w * 1024 + c * 512]);
            gload_lds16(BT + (size_t)(n0 + rowA + c * 16) * 2048 + k0 + colb,
                        &Bs[w * 1024 + c * 512]);
        }
        __syncthreads();
        short8 af[4], bfr[4];
#pragma unroll
        for (int m = 0; m < 4; m++)
            af[m] = *(const short8*)&As[(wr * 64 + m * 16 + l15) * 32 + lh * 8];
#pragma unroll
        for (int n = 0; n < 4; n++)
            bfr[n] = *(const short8*)&Bs[(wc * 64 + n * 16 + l15) * 32 + lh * 8];
#pragma unroll
        for (int m = 0; m < 4; m++)
#pragma unroll
            for (int n = 0; n < 4; n++)
                acc[m][n] = mfma16(af[m], bfr[n], acc[m][n]);
    }

    const int rbase = m0 + wr * 64 + lh * 4;
    const int cloc = wc * 64 + l15;

    if (blockIdx.x < 16) {            // Q region
        const int cbase = n0 + cloc;
#pragma unroll
        for (int m = 0; m < 4; m++)
#pragma unroll
            for (int j = 0; j < 4; j++) {
                size_t ro = (size_t)(rbase + m * 16 + j) * 2048 + cbase;
#pragma unroll
                for (int n = 0; n < 4; n++)
                    Qo[ro + n * 16] = f2bf(acc[m][n][j]);
            }
    } else if (blockIdx.x < 24) {     // K region
        const int cbase = (n0 - 2048) + cloc;
#pragma unroll
        for (int m = 0; m < 4; m++)
#pragma unroll
            for (int j = 0; j < 4; j++) {
                size_t ro = (size_t)(rbase + m * 16 + j) * 1024 + cbase;
#pragma unroll
                for (int n = 0; n < 4; n++)
                    Ko[ro + n * 16] = f2bf(acc[m][n][j]);
            }
    } else {                          // V region -> V^T[b][h2][d][s]
        const int cbase = (n0 - 3072) + cloc;
#pragma unroll
        for (int m = 0; m < 4; m++)
#pragma unroll
            for (int n = 0; n < 4; n++) {
                int r = rbase + m * 16;
                int c = cbase + n * 16;
                int bb = r >> 11, ss = r & 2047;
                int h2 = c >> 7, d = c & 127;
                uint2 v;
                v.x = (u32)f2bf(acc[m][n][0]) | ((u32)f2bf(acc[m][n][1]) << 16);
                v.y = (u32)f2bf(acc[m][n][2]) | ((u32)f2bf(acc[m][n][3]) << 16);
                *(uint2*)(Vo + (size_t)((bb * 8 + h2) * 128 + d) * 2048 + ss) = v;
            }
    }
}

// ---------------- m97-style bf16 GEMM, f32 out (Wo GEMM) ----------------
__global__ __launch_bounds__(256) void gemm_wo(const u16* __restrict__ A,
                                               const u16* __restrict__ BT,
                                               float* __restrict__ Of,
                                               int M, int N, int K) {
    __shared__ u16 As[128 * 32];
    __shared__ u16 Bs[128 * 32];
    const int tid = threadIdx.x;
    const int w = tid >> 6, l = tid & 63;
    const int m0 = blockIdx.y * 128, n0 = blockIdx.x * 128;
    const int wr = w >> 1, wc = w & 1;
    const int l15 = l & 15, lh = l >> 4;

    const f32x4 fz = {0.f, 0.f, 0.f, 0.f};
    f32x4 acc[4][4];
#pragma unroll
    for (int m = 0; m < 4; m++)
#pragma unroll
        for (int n = 0; n < 4; n++) acc[m][n] = fz;

    const int rowA = w * 32 + (l >> 2);
    const int colb = (l & 3) * 8;

    for (int k0 = 0; k0 < K; k0 += 32) {
        __syncthreads();
#pragma unroll
        for (int c = 0; c < 2; c++) {
            gload_lds16(A  + (size_t)(m0 + rowA + c * 16) * K + k0 + colb,
                        &As[w * 1024 + c * 512]);
            gload_lds16(BT + (size_t)(n0 + rowA + c * 16) * K + k0 + colb,
                        &Bs[w * 1024 + c * 512]);
        }
        __syncthreads();
        short8 af[4], bfr[4];
#pragma unroll
        for (int m = 0; m < 4; m++)
            af[m] = *(const short8*)&As[(wr * 64 + m * 16 + l15) * 32 + lh * 8];
#pragma unroll
        for (int n = 0; n < 4; n++)
            bfr[n] = *(const short8*)&Bs[(wc * 64 + n * 16 + l15) * 32 + lh * 8];
#pragma unroll
        for (int m = 0; m < 4; m++)
#pragma unroll
            for (int n = 0; n < 4; n++)
                acc[m][n] = mfma16(af[m], bfr[n], acc[m][n]);
    }

    const int rbase = m0 + wr * 64 + lh * 4;
    const int cbase = n0 + wc * 64 + l15;
#pragma unroll
    for (int m = 0; m < 4; m++)
#pragma unroll
        for (int j = 0; j < 4; j++) {
            size_t ro = (size_t)(rbase + m * 16 + j) * N + cbase;
#pragma unroll
            for (int n = 0; n < 4; n++)
                Of[ro + n * 16] = acc[m][n][j];
        }
}

// ---------------- flash attention (non-causal, GQA), swapped QK^T ----------------
// grid (32 qtiles, 32 b*h); block 256 = 4 waves; wave owns 16 q rows.
// LDS: Ks [64][128] u16, Vs [128][64] u16 (V^T), Ps [wave][16][64] u16 — all
// XOR-swizzled: byte ^= (row&7)<<4 (T2 / m214 recipe, linear layout).
__global__ __launch_bounds__(256) void attn_kernel(const u16* __restrict__ Q,
                                                   const u16* __restrict__ Kg,
                                                   const u16* __restrict__ Vg,
                                                   u16* __restrict__ O) {
    __shared__ u16 Ks[64 * 128];
    __shared__ u16 Vs[128 * 64];
    __shared__ u16 Ps[4][1024];
    const int tid = threadIdx.x;
    const int w = tid >> 6, l = tid & 63;
    const int qt = blockIdx.x, bh = blockIdx.y;
    const int b = bh >> 4, h = bh & 15, h2 = h >> 1;
    const int l15 = l & 15, lh = l >> 4;
    const int swz = (l15 & 7) << 4;
    char* KsB = (char*)Ks;
    char* VsB = (char*)Vs;
    char* PsB = (char*)Ps + w * 2048;

    // Q fragments (already scaled by 1/sqrt(128) in rope): B-operand, col = l15
    short8 qf[4];
    {
        const int qrow = qt * 64 + w * 16 + l15;
        const u16* qp = Q + ((size_t)(b * 2048 + qrow)) * 2048 + h * 128 + lh * 8;
#pragma unroll
        for (int ks = 0; ks < 4; ks++) qf[ks] = *(const short8*)(qp + ks * 32);
    }
    const f32x4 fz = {0.f, 0.f, 0.f, 0.f};
    f32x4 o[8];
#pragma unroll
    for (int n = 0; n < 8; n++) o[n] = fz;
    float mrun = -1e30f, lsum = 0.f;   // per-lane, for q-row = l15

    const int krow = tid >> 4, kcb = (tid & 15) * 8;
    const int vrow = tid >> 3, vcb = (tid & 7) * 8;

    for (int t = 0; t < 32; t++) {
        __syncthreads();
        {
            const size_t kgb = ((size_t)(b * 2048 + t * 64)) * 1024 + h2 * 128;
#pragma unroll
            for (int i = 0; i < 4; i++) {
                int r = i * 16 + krow;
                u32x4 v = *(const u32x4*)(Kg + kgb + (size_t)r * 1024 + kcb);
                *(u32x4*)(KsB + ((r * 256 + kcb * 2) ^ ((r & 7) << 4))) = v;
            }
            const size_t vgb = ((size_t)((b * 8 + h2) * 128)) * 2048 + t * 64;
#pragma unroll
            for (int i = 0; i < 4; i++) {
                int d = i * 32 + vrow;
                u32x4 v = *(const u32x4*)(Vg + vgb + (size_t)d * 2048 + vcb);
                *(u32x4*)(VsB + ((d * 128 + vcb * 2) ^ ((d & 7) << 4))) = v;
            }
        }
        __syncthreads();

        // S^T = K·Q^T: s[ct][r] = S[key = ct*16+lh*4+r][q = l15]
        f32x4 s[4];
#pragma unroll
        for (int ct = 0; ct < 4; ct++) {
            s[ct] = fz;
#pragma unroll
            for (int ks = 0; ks < 4; ks++) {
                short8 kf = *(const short8*)(KsB +
                    (((ct * 16 + l15) * 256 + ks * 64 + lh * 16) ^ swz));
                s[ct] = mfma16(kf, qf[ks], s[ct]);
            }
        }

        // online softmax for q = l15 (4 lanes per q cooperate via shfl 16/32)
        float mx = s[0][0];
#pragma unroll
        for (int ct = 0; ct < 4; ct++)
#pragma unroll
            for (int r = 0; r < 4; r++) mx = fmaxf(mx, s[ct][r]);
        mx = fmaxf(mx, __shfl_xor(mx, 16));
        mx = fmaxf(mx, __shfl_xor(mx, 32));
        float mnew = fmaxf(mrun, mx);
        float fsc = __expf(mrun - mnew);
        mrun = mnew;

        float ps = 0.f;
#pragma unroll
        for (int ct = 0; ct < 4; ct++) {
            float p0 = __expf(s[ct][0] - mnew);
            float p1 = __expf(s[ct][1] - mnew);
            float p2 = __expf(s[ct][2] - mnew);
            float p3 = __expf(s[ct][3] - mnew);
            ps += (p0 + p1) + (p2 + p3);
            uint2 pw;
            pw.x = (u32)f2bf(p0) | ((u32)f2bf(p1) << 16);
            pw.y = (u32)f2bf(p2) | ((u32)f2bf(p3) << 16);
            // P[q=l15][k = ct*16 + lh*4 .. +3]
            *(uint2*)(PsB + ((l15 * 128 + ct * 32 + lh * 8) ^ swz)) = pw;
        }
        ps += __shfl_xor(ps, 16);
        ps += __shfl_xor(ps, 32);
        lsum = lsum * fsc + ps;

        // rescale o (rows q = lh*4+r) by that q's fsc
#pragma unroll
        for (int r = 0; r < 4; r++) {
            float fr = __shfl(fsc, lh * 4 + r);
#pragma unroll
            for (int n = 0; n < 8; n++) o[n][r] *= fr;
        }

        // PV: o[q][d] += P[q][k] * V^T[d][k]
#pragma unroll
        for (int ks2 = 0; ks2 < 2; ks2++) {
            short8 pf = *(const short8*)(PsB +
                ((l15 * 128 + ks2 * 64 + lh * 16) ^ swz));
#pragma unroll
            for (int n = 0; n < 8; n++) {
                short8 vf = *(const short8*)(VsB +
                    (((n * 16 + l15) * 128 + ks2 * 64 + lh * 16) ^ swz));
                o[n] = mfma16(pf, vf, o[n]);
            }
        }
    }

    const size_t ob = ((size_t)(b * 2048 + qt * 64 + w * 16 + lh * 4)) * 2048 + h * 128 + l15;
#pragma unroll
    for (int r = 0; r < 4; r++) {
        float lq = __shfl(lsum, lh * 4 + r);
        float li = 1.0f / lq;
#pragma unroll
        for (int n = 0; n < 8; n++)
            O[ob + (size_t)r * 2048 + n * 16] = f2bf(o[n][r] * li);
    }
}

// ---------------- launch ----------------
extern "C" void kernel_launch(void* const* d_in, const int* in_sizes, int n_in,
                              void* d_out, int out_size, void* d_ws, size_t ws_size,
                              hipStream_t stream) {
    const float* x  = (const float*)d_in[0];
    const float* Wq = (const float*)d_in[1];
    const float* Wk = (const float*)d_in[2];
    const float* Wv = (const float*)d_in[3];
    const float* Wo = (const float*)d_in[4];
    const float* fc = (const float*)d_in[5];
    const float* fs = (const float*)d_in[6];
    float* out = (float*)d_out;

    uint8_t* ws = (uint8_t*)d_ws;
    u16* xb   = (u16*)(ws + 0);          // 16.8 MB  (aliased as attn_out later)
    u16* wqkv = (u16*)(ws + 16777216);   // 16.8 MB: wqT | wkT | wvT contiguous
    u16* wqT  = (u16*)(ws + 16777216);
    u16* wkT  = (u16*)(ws + 25165824);
    u16* wvT  = (u16*)(ws + 29360128);
    u16* woT  = (u16*)(ws + 33554432);   // 8.4 MB
    u16* qb   = (u16*)(ws + 41943040);   // 16.8 MB
    u16* kb   = (u16*)(ws + 58720256);   // 8.4 MB
    u16* vT   = (u16*)(ws + 67108864);   // 8.4 MB   total 75.5 MB
    u16* ao   = xb;                      // alias: x_bf16 dead after QKV gemm

    cvt_x<<<dim3(8192), dim3(256), 0, stream>>>(x, xb, 2097152);
    transpose_cvt<<<dim3(32, 32), dim3(256), 0, stream>>>(Wq, wqT, 2048, 2048);
    transpose_cvt<<<dim3(16, 32), dim3(256), 0, stream>>>(Wk, wkT, 2048, 1024);
    transpose_cvt<<<dim3(16, 32), dim3(256), 0, stream>>>(Wv, wvT, 2048, 1024);
    transpose_cvt<<<dim3(32, 32), dim3(256), 0, stream>>>(Wo, woT, 2048, 2048);

    gemm_qkv<<<dim3(32, 32), dim3(256), 0, stream>>>(xb, wqkv, qb, kb, vT);

    rope_kernel<<<dim3(16384), dim3(256), 0, stream>>>(qb, fc, fs, 16, 10, 4194304,
                                                       0.08838834764831845f);
    rope_kernel<<<dim3(8192),  dim3(256), 0, stream>>>(kb, fc, fs, 8, 9, 2097152, 1.0f);

    attn_kernel<<<dim3(32, 32), dim3(256), 0, stream>>>(qb, kb, vT, ao);

    gemm_wo<<<dim3(16, 32), dim3(256), 0, stream>>>(ao, woT, out, 4096, 2048, 2048);
}

// Round 4
// 312.471 us; speedup vs baseline: 1.4313x; 1.4313x over previous
//
#include <hip/hip_runtime.h>
#include <stdint.h>

#define DI __device__ __forceinline__

typedef unsigned short u16;
typedef unsigned int   u32;
typedef __attribute__((ext_vector_type(8))) short short8;
typedef __attribute__((ext_vector_type(4))) float f32x4;

// ---- constants (problem shape hardcoded) ----
// B=2, S=2048, HID=2048, HQ=16, HKV=8, D=128

DI u16 f2bf(float f) {
    u32 u = __float_as_uint(f);
    u32 r = u + 0x7fff + ((u >> 16) & 1);   // RNE
    return (u16)(r >> 16);
}
DI u32 pk2bf(float a, float b) {
    return (u32)f2bf(a) | ((u32)f2bf(b) << 16);
}
DI float bf2f(u16 h) { return __uint_as_float(((u32)h) << 16); }

DI f32x4 mfma16(short8 a, short8 b, f32x4 c) {
    return __builtin_amdgcn_mfma_f32_16x16x32_bf16(a, b, c, 0, 0, 0);
}

DI void gload_lds16(const void* g, void* l) {
    __builtin_amdgcn_global_load_lds(
        (const __attribute__((address_space(1))) void*)g,
        (__attribute__((address_space(3))) void*)l, 16, 0, 0);
}

// ---------------- convert x f32 -> bf16 ----------------
__global__ __launch_bounds__(256) void cvt_x(const float* __restrict__ x,
                                             u16* __restrict__ o, int n4) {
    int i = blockIdx.x * 256 + threadIdx.x;
    if (i >= n4) return;
    float4 v = *(const float4*)(x + (size_t)i * 4);
    uint2 p; p.x = pk2bf(v.x, v.y); p.y = pk2bf(v.z, v.w);
    *(uint2*)(o + (size_t)i * 4) = p;
}

// ---------------- W [K][N] f32 -> WT [N][K] bf16 ----------------
__global__ __launch_bounds__(256) void transpose_cvt(const float* __restrict__ W,
                                                     u16* __restrict__ WT,
                                                     int K, int N) {
    __shared__ u16 tl[64][65];
    int tx = threadIdx.x & 15, ty = threadIdx.x >> 4;
    int tc = blockIdx.x * 64, tr = blockIdx.y * 64;
#pragma unroll
    for (int i = 0; i < 4; i++) {
        int r = tr + ty + i * 16;
        float4 v = *(const float4*)&W[(size_t)r * N + tc + tx * 4];
        tl[tx*4+0][ty+i*16] = f2bf(v.x);
        tl[tx*4+1][ty+i*16] = f2bf(v.y);
        tl[tx*4+2][ty+i*16] = f2bf(v.z);
        tl[tx*4+3][ty+i*16] = f2bf(v.w);
    }
    __syncthreads();
#pragma unroll
    for (int i = 0; i < 4; i++) {
        int n = tc + ty + i * 16;
        uint2 p;
        p.x = (u32)tl[ty+i*16][tx*4+0] | ((u32)tl[ty+i*16][tx*4+1] << 16);
        p.y = (u32)tl[ty+i*16][tx*4+2] | ((u32)tl[ty+i*16][tx*4+3] << 16);
        *(uint2*)&WT[(size_t)n * K + tr + tx * 4] = p;
    }
}

// ---------------- RoPE in-place on bf16 [tok][H*128], output scaled ----------------
__global__ __launch_bounds__(256) void rope_kernel(u16* __restrict__ buf,
                                                   const float* __restrict__ fc,
                                                   const float* __restrict__ fs,
                                                   int H, int tokshift, int total,
                                                   float oscale) {
    int idx = blockIdx.x * 256 + threadIdx.x;
    if (idx >= total) return;
    int tok = idx >> tokshift;
    int rem = idx & ((1 << tokshift) - 1);
    int h = rem >> 6, j = rem & 63;
    int s = tok & 2047;
    size_t a = ((size_t)tok * H + h) * 128 + 2 * j;
    u32 v = *(u32*)(buf + a);
    float re = bf2f((u16)(v & 0xffff));
    float im = bf2f((u16)(v >> 16));
    float c = fc[s * 64 + j], sn = fs[s * 64 + j];
    *(u32*)(buf + a) = pk2bf((re * c - im * sn) * oscale,
                             (re * sn + im * c) * oscale);
}

// ---------------- fused QKV GEMM: A[4096][2048] * WqkvT[4096][2048] ----------------
__global__ __launch_bounds__(256) void gemm_qkv(const u16* __restrict__ A,
                                                const u16* __restrict__ BT,
                                                u16* __restrict__ Qo,
                                                u16* __restrict__ Ko,
                                                u16* __restrict__ Vo) {
    __shared__ u16 As[128 * 32];
    __shared__ u16 Bs[128 * 32];
    const int tid = threadIdx.x;
    const int w = tid >> 6, l = tid & 63;
    const int m0 = blockIdx.y * 128, n0 = blockIdx.x * 128;
    const int wr = w >> 1, wc = w & 1;
    const int l15 = l & 15, lh = l >> 4;

    const f32x4 fz = {0.f, 0.f, 0.f, 0.f};
    f32x4 acc[4][4];
#pragma unroll
    for (int m = 0; m < 4; m++)
#pragma unroll
        for (int n = 0; n < 4; n++) acc[m][n] = fz;

    const int rowA = w * 32 + (l >> 2);
    const int colb = (l & 3) * 8;

    for (int k0 = 0; k0 < 2048; k0 += 32) {
        __syncthreads();
#pragma unroll
        for (int c = 0; c < 2; c++) {
            gload_lds16(A  + (size_t)(m0 + rowA + c * 16) * 2048 + k0 + colb,
                        &As[w * 1024 + c * 512]);
            gload_lds16(BT + (size_t)(n0 + rowA + c * 16) * 2048 + k0 + colb,
                        &Bs[w * 1024 + c * 512]);
        }
        __syncthreads();
        short8 af[4], bfr[4];
#pragma unroll
        for (int m = 0; m < 4; m++)
            af[m] = *(const short8*)&As[(wr * 64 + m * 16 + l15) * 32 + lh * 8];
#pragma unroll
        for (int n = 0; n < 4; n++)
            bfr[n] = *(const short8*)&Bs[(wc * 64 + n * 16 + l15) * 32 + lh * 8];
#pragma unroll
        for (int m = 0; m < 4; m++)
#pragma unroll
            for (int n = 0; n < 4; n++)
                acc[m][n] = mfma16(af[m], bfr[n], acc[m][n]);
    }

    const int rbase = m0 + wr * 64 + lh * 4;
    const int cloc = wc * 64 + l15;

    if (blockIdx.x < 16) {            // Q region
        const int cbase = n0 + cloc;
#pragma unroll
        for (int m = 0; m < 4; m++)
#pragma unroll
            for (int j = 0; j < 4; j++) {
                size_t ro = (size_t)(rbase + m * 16 + j) * 2048 + cbase;
#pragma unroll
                for (int n = 0; n < 4; n++)
                    Qo[ro + n * 16] = f2bf(acc[m][n][j]);
            }
    } else if (blockIdx.x < 24) {     // K region
        const int cbase = (n0 - 2048) + cloc;
#pragma unroll
        for (int m = 0; m < 4; m++)
#pragma unroll
            for (int j = 0; j < 4; j++) {
                size_t ro = (size_t)(rbase + m * 16 + j) * 1024 + cbase;
#pragma unroll
                for (int n = 0; n < 4; n++)
                    Ko[ro + n * 16] = f2bf(acc[m][n][j]);
            }
    } else {                          // V region -> V^T[b][h2][d][s]
        const int cbase = (n0 - 3072) + cloc;
#pragma unroll
        for (int m = 0; m < 4; m++)
#pragma unroll
            for (int n = 0; n < 4; n++) {
                int r = rbase + m * 16;
                int c = cbase + n * 16;
                int bb = r >> 11, ss = r & 2047;
                int h2 = c >> 7, d = c & 127;
                uint2 v;
                v.x = pk2bf(acc[m][n][0], acc[m][n][1]);
                v.y = pk2bf(acc[m][n][2], acc[m][n][3]);
                *(uint2*)(Vo + (size_t)((bb * 8 + h2) * 128 + d) * 2048 + ss) = v;
            }
    }
}

// ---------------- m97-style bf16 GEMM, f32 out (Wo GEMM) ----------------
__global__ __launch_bounds__(256) void gemm_wo(const u16* __restrict__ A,
                                               const u16* __restrict__ BT,
                                               float* __restrict__ Of,
                                               int M, int N, int K) {
    __shared__ u16 As[128 * 32];
    __shared__ u16 Bs[128 * 32];
    const int tid = threadIdx.x;
    const int w = tid >> 6, l = tid & 63;
    const int m0 = blockIdx.y * 128, n0 = blockIdx.x * 128;
    const int wr = w >> 1, wc = w & 1;
    const int l15 = l & 15, lh = l >> 4;

    const f32x4 fz = {0.f, 0.f, 0.f, 0.f};
    f32x4 acc[4][4];
#pragma unroll
    for (int m = 0; m < 4; m++)
#pragma unroll
        for (int n = 0; n < 4; n++) acc[m][n] = fz;

    const int rowA = w * 32 + (l >> 2);
    const int colb = (l & 3) * 8;

    for (int k0 = 0; k0 < K; k0 += 32) {
        __syncthreads();
#pragma unroll
        for (int c = 0; c < 2; c++) {
            gload_lds16(A  + (size_t)(m0 + rowA + c * 16) * K + k0 + colb,
                        &As[w * 1024 + c * 512]);
            gload_lds16(BT + (size_t)(n0 + rowA + c * 16) * K + k0 + colb,
                        &Bs[w * 1024 + c * 512]);
        }
        __syncthreads();
        short8 af[4], bfr[4];
#pragma unroll
        for (int m = 0; m < 4; m++)
            af[m] = *(const short8*)&As[(wr * 64 + m * 16 + l15) * 32 + lh * 8];
#pragma unroll
        for (int n = 0; n < 4; n++)
            bfr[n] = *(const short8*)&Bs[(wc * 64 + n * 16 + l15) * 32 + lh * 8];
#pragma unroll
        for (int m = 0; m < 4; m++)
#pragma unroll
            for (int n = 0; n < 4; n++)
                acc[m][n] = mfma16(af[m], bfr[n], acc[m][n]);
    }

    const int rbase = m0 + wr * 64 + lh * 4;
    const int cbase = n0 + wc * 64 + l15;
#pragma unroll
    for (int m = 0; m < 4; m++)
#pragma unroll
        for (int j = 0; j < 4; j++) {
            size_t ro = (size_t)(rbase + m * 16 + j) * N + cbase;
#pragma unroll
            for (int n = 0; n < 4; n++)
                Of[ro + n * 16] = acc[m][n][j];
        }
}

// ---------------- flash attention (non-causal, GQA) ----------------
// grid (16 qtiles of 128 rows, 32 b*h); block 512 = 8 waves; wave owns 16 q rows.
// K/V double-buffered, staged by global_load_lds with pre-swizzled SOURCE
// (linear LDS dest, m173 pattern); one __syncthreads per tile.
// Softmax in exp2 domain (Q pre-scaled by log2e/sqrt(128)); defer-max THR=8.
__global__ __launch_bounds__(512, 4) void attn_kernel(const u16* __restrict__ Q,
                                                      const u16* __restrict__ Kg,
                                                      const u16* __restrict__ Vg,
                                                      u16* __restrict__ O) {
    __shared__ __align__(16) u16 Ks[2][8192];  // [buf][key 64][128] swizzled
    __shared__ __align__(16) u16 Vs[2][8192];  // [buf][d 128][64]  swizzled (V^T)
    __shared__ __align__(16) u16 Ps[8][1024];  // per-wave P [q16][k64] swizzled
    const int tid = threadIdx.x;
    const int w = tid >> 6, l = tid & 63;
    const int qt = blockIdx.x, bh = blockIdx.y;
    const int b = bh >> 4, h = bh & 15, h2 = h >> 1;
    const int l15 = l & 15, lh = l >> 4;

    char* KsB = (char*)&Ks[0][0];
    char* VsB = (char*)&Vs[0][0];
    char* PsB = (char*)&Ps[w][0];

    // staging geometry: block stages K tile (16KB) + V tile (16KB) in 2 issues each
    const char* Kbase = (const char*)Kg + (size_t)b * 2048 * 2048 + h2 * 256;
    const char* Vbase = (const char*)Vg + (size_t)(b * 8 + h2) * 128 * 4096;
    const int X0 = tid * 16, X1 = 8192 + tid * 16;
    const int kr0 = X0 >> 8, kc0 = (X0 & 255) ^ ((kr0 & 7) << 4);
    const int kr1 = X1 >> 8, kc1 = (X1 & 255) ^ ((kr1 & 7) << 4);
    const int vd0 = X0 >> 7, vc0 = (X0 & 127) ^ ((vd0 & 7) << 4);
    const int vd1 = X1 >> 7, vc1 = (X1 & 127) ^ ((vd1 & 7) << 4);
    const int wb = w << 10;   // wave-uniform LDS dest base (bytes)

#define STAGE(t, pb) do {                                              \
        const char* Kt = Kbase + (size_t)(t) * 131072;                 \
        const char* Vt = Vbase + (t) * 128;                            \
        char* kd = KsB + (pb) * 16384;                                 \
        char* vd = VsB + (pb) * 16384;                                 \
        gload_lds16(Kt + kr0 * 2048 + kc0, kd + wb);                   \
        gload_lds16(Kt + kr1 * 2048 + kc1, kd + 8192 + wb);            \
        gload_lds16(Vt + vd0 * 4096 + vc0, vd + wb);                   \
        gload_lds16(Vt + vd1 * 4096 + vc1, vd + 8192 + wb);            \
    } while (0)

    // Q fragments (pre-scaled by log2e/sqrt(128) in rope); A-operand, row = l15
    short8 qf[4];
    {
        const u16* qp = Q + ((size_t)(b * 2048 + qt * 128 + w * 16 + l15)) * 2048
                          + h * 128 + lh * 8;
#pragma unroll
        for (int ks = 0; ks < 4; ks++) qf[ks] = *(const short8*)(qp + ks * 32);
    }

    const f32x4 fz = {0.f, 0.f, 0.f, 0.f};
    f32x4 o[8];
#pragma unroll
    for (int n = 0; n < 8; n++) o[n] = fz;
    float mrow[4] = {-1e30f, -1e30f, -1e30f, -1e30f};
    float lsum[4] = {0.f, 0.f, 0.f, 0.f};

    STAGE(0, 0);

    for (int t = 0; t < 32; t++) {
        __syncthreads();                 // drains vmcnt(0): stage(t) landed
        const int pb = t & 1;
        if (t < 31) STAGE(t + 1, pb ^ 1);
        const char* kc = KsB + pb * 16384;
        const char* vc = VsB + pb * 16384;
        const int swz = (l15 & 7) << 4;

        // S = Q·K^T: s[ct][r] = S[q = lh*4+r][key = ct*16+l15] (log2 domain)
        f32x4 s[4];
#pragma unroll
        for (int ct = 0; ct < 4; ct++) {
            s[ct] = fz;
#pragma unroll
            for (int ks = 0; ks < 4; ks++) {
                short8 kf = *(const short8*)(kc + ((ct * 16 + l15) << 8)
                                                + ((ks * 64 + lh * 16) ^ swz));
                s[ct] = mfma16(qf[ks], kf, s[ct]);
            }
        }

        // defer-max online softmax (all lane-local except the sum reduce)
        float pl[4];
#pragma unroll
        for (int r = 0; r < 4; r++)
            pl[r] = fmaxf(fmaxf(s[0][r], s[1][r]), fmaxf(s[2][r], s[3][r]));
        bool grow = (pl[0] > mrow[0] + 8.f) || (pl[1] > mrow[1] + 8.f) ||
                    (pl[2] > mrow[2] + 8.f) || (pl[3] > mrow[3] + 8.f);
        if (__any(grow)) {
#pragma unroll
            for (int r = 0; r < 4; r++) {
                float mx = pl[r];
                mx = fmaxf(mx, __shfl_xor(mx, 1));
                mx = fmaxf(mx, __shfl_xor(mx, 2));
                mx = fmaxf(mx, __shfl_xor(mx, 4));
                mx = fmaxf(mx, __shfl_xor(mx, 8));
                float mnew = fmaxf(mrow[r], mx);
                float fsc = exp2f(mrow[r] - mnew);
                mrow[r] = mnew;
                lsum[r] *= fsc;
#pragma unroll
                for (int n = 0; n < 8; n++) o[n][r] *= fsc;
            }
        }
#pragma unroll
        for (int r = 0; r < 4; r++) {
            float p0 = exp2f(s[0][r] - mrow[r]);
            float p1 = exp2f(s[1][r] - mrow[r]);
            float p2 = exp2f(s[2][r] - mrow[r]);
            float p3 = exp2f(s[3][r] - mrow[r]);
            float ps = (p0 + p1) + (p2 + p3);
            ps += __shfl_xor(ps, 1);
            ps += __shfl_xor(ps, 2);
            ps += __shfl_xor(ps, 4);
            ps += __shfl_xor(ps, 8);
            lsum[r] += ps;
            // P[q = lh*4+r][key = ct*16+l15], swizzle byte ^= ((row>>2)&3)<<4 = lh<<4
            const int rb = ((lh * 4 + r) << 7);
            *(u16*)(PsB + ((rb + ((0 * 16 + l15) << 1)) ^ (lh << 4))) = f2bf(p0);
            *(u16*)(PsB + ((rb + ((1 * 16 + l15) << 1)) ^ (lh << 4))) = f2bf(p1);
            *(u16*)(PsB + ((rb + ((2 * 16 + l15) << 1)) ^ (lh << 4))) = f2bf(p2);
            *(u16*)(PsB + ((rb + ((3 * 16 + l15) << 1)) ^ (lh << 4))) = f2bf(p3);
        }

        // PV: o[q][d] += P[q][k] * V^T[d][k]
#pragma unroll
        for (int ks2 = 0; ks2 < 2; ks2++) {
            short8 pf = *(const short8*)(PsB + (((l15 << 7) + ks2 * 64 + lh * 16)
                                                ^ (((l15 >> 2) & 3) << 4)));
#pragma unroll
            for (int n = 0; n < 8; n++) {
                short8 vf = *(const short8*)(vc + (((n * 16 + l15) << 7)
                                                  + ((ks2 * 64 + lh * 16) ^ swz)));
                o[n] = mfma16(pf, vf, o[n]);
            }
        }
    }

    const size_t ob = ((size_t)(b * 2048 + qt * 128 + w * 16 + lh * 4)) * 2048
                      + h * 128 + l15;
#pragma unroll
    for (int r = 0; r < 4; r++) {
        float li = 1.0f / lsum[r];
#pragma unroll
        for (int n = 0; n < 8; n++)
            O[ob + (size_t)r * 2048 + n * 16] = f2bf(o[n][r] * li);
    }
#undef STAGE
}

// ---------------- launch ----------------
extern "C" void kernel_launch(void* const* d_in, const int* in_sizes, int n_in,
                              void* d_out, int out_size, void* d_ws, size_t ws_size,
                              hipStream_t stream) {
    const float* x  = (const float*)d_in[0];
    const float* Wq = (const float*)d_in[1];
    const float* Wk = (const float*)d_in[2];
    const float* Wv = (const float*)d_in[3];
    const float* Wo = (const float*)d_in[4];
    const float* fc = (const float*)d_in[5];
    const float* fs = (const float*)d_in[6];
    float* out = (float*)d_out;

    uint8_t* ws = (uint8_t*)d_ws;
    u16* xb   = (u16*)(ws + 0);          // 16.8 MB  (aliased as attn_out later)
    u16* wqkv = (u16*)(ws + 16777216);   // 16.8 MB: wqT | wkT | wvT contiguous
    u16* wqT  = (u16*)(ws + 16777216);
    u16* wkT  = (u16*)(ws + 25165824);
    u16* wvT  = (u16*)(ws + 29360128);
    u16* woT  = (u16*)(ws + 33554432);   // 8.4 MB
    u16* qb   = (u16*)(ws + 41943040);   // 16.8 MB
    u16* kb   = (u16*)(ws + 58720256);   // 8.4 MB
    u16* vT   = (u16*)(ws + 67108864);   // 8.4 MB   total 75.5 MB
    u16* ao   = xb;                      // alias: x_bf16 dead after QKV gemm

    cvt_x<<<dim3(8192), dim3(256), 0, stream>>>(x, xb, 2097152);
    transpose_cvt<<<dim3(32, 32), dim3(256), 0, stream>>>(Wq, wqT, 2048, 2048);
    transpose_cvt<<<dim3(16, 32), dim3(256), 0, stream>>>(Wk, wkT, 2048, 1024);
    transpose_cvt<<<dim3(16, 32), dim3(256), 0, stream>>>(Wv, wvT, 2048, 1024);
    transpose_cvt<<<dim3(32, 32), dim3(256), 0, stream>>>(Wo, woT, 2048, 2048);

    gemm_qkv<<<dim3(32, 32), dim3(256), 0, stream>>>(xb, wqkv, qb, kb, vT);

    // Q carries (1/sqrt(128)) * log2(e) so softmax runs in exp2 domain
    rope_kernel<<<dim3(16384), dim3(256), 0, stream>>>(qb, fc, fs, 16, 10, 4194304,
                                                       0.12751742987f);
    rope_kernel<<<dim3(8192),  dim3(256), 0, stream>>>(kb, fc, fs, 8, 9, 2097152, 1.0f);

    attn_kernel<<<dim3(16, 32), dim3(512), 0, stream>>>(qb, kb, vT, ao);

    gemm_wo<<<dim3(16, 32), dim3(256), 0, stream>>>(ao, woT, out, 4096, 2048, 2048);
}

// Round 5
// 293.038 us; speedup vs baseline: 1.5263x; 1.0663x over previous
//
#include <hip/hip_runtime.h>
#include <stdint.h>

#define DI __device__ __forceinline__

typedef unsigned short u16;
typedef unsigned int   u32;
typedef __attribute__((ext_vector_type(8))) short short8;
typedef __attribute__((ext_vector_type(4))) float f32x4;

// ---- constants (problem shape hardcoded) ----
// B=2, S=2048, HID=2048, HQ=16, HKV=8, D=128

DI u16 f2bf(float f) {
    u32 u = __float_as_uint(f);
    u32 r = u + 0x7fff + ((u >> 16) & 1);   // RNE
    return (u16)(r >> 16);
}
DI u32 pk2bf(float a, float b) {
    return (u32)f2bf(a) | ((u32)f2bf(b) << 16);
}
DI float bf2f(u16 h) { return __uint_as_float(((u32)h) << 16); }

DI f32x4 mfma16(short8 a, short8 b, f32x4 c) {
    return __builtin_amdgcn_mfma_f32_16x16x32_bf16(a, b, c, 0, 0, 0);
}

DI void gload_lds16(const void* g, void* l) {
    __builtin_amdgcn_global_load_lds(
        (const __attribute__((address_space(1))) void*)g,
        (__attribute__((address_space(3))) void*)l, 16, 0, 0);
}

// ---------------- convert x f32 -> bf16 ----------------
__global__ __launch_bounds__(256) void cvt_x(const float* __restrict__ x,
                                             u16* __restrict__ o, int n4) {
    int i = blockIdx.x * 256 + threadIdx.x;
    if (i >= n4) return;
    float4 v = *(const float4*)(x + (size_t)i * 4);
    uint2 p; p.x = pk2bf(v.x, v.y); p.y = pk2bf(v.z, v.w);
    *(uint2*)(o + (size_t)i * 4) = p;
}

// ---------------- W [K][N] f32 -> WT [N][K] bf16 ----------------
__global__ __launch_bounds__(256) void transpose_cvt(const float* __restrict__ W,
                                                     u16* __restrict__ WT,
                                                     int K, int N) {
    __shared__ u16 tl[64][65];
    int tx = threadIdx.x & 15, ty = threadIdx.x >> 4;
    int tc = blockIdx.x * 64, tr = blockIdx.y * 64;
#pragma unroll
    for (int i = 0; i < 4; i++) {
        int r = tr + ty + i * 16;
        float4 v = *(const float4*)&W[(size_t)r * N + tc + tx * 4];
        tl[tx*4+0][ty+i*16] = f2bf(v.x);
        tl[tx*4+1][ty+i*16] = f2bf(v.y);
        tl[tx*4+2][ty+i*16] = f2bf(v.z);
        tl[tx*4+3][ty+i*16] = f2bf(v.w);
    }
    __syncthreads();
#pragma unroll
    for (int i = 0; i < 4; i++) {
        int n = tc + ty + i * 16;
        uint2 p;
        p.x = (u32)tl[ty+i*16][tx*4+0] | ((u32)tl[ty+i*16][tx*4+1] << 16);
        p.y = (u32)tl[ty+i*16][tx*4+2] | ((u32)tl[ty+i*16][tx*4+3] << 16);
        *(uint2*)&WT[(size_t)n * K + tr + tx * 4] = p;
    }
}

// ---------------- RoPE in-place on bf16 [tok][H*128], output scaled ----------------
__global__ __launch_bounds__(256) void rope_kernel(u16* __restrict__ buf,
                                                   const float* __restrict__ fc,
                                                   const float* __restrict__ fs,
                                                   int H, int tokshift, int total,
                                                   float oscale) {
    int idx = blockIdx.x * 256 + threadIdx.x;
    if (idx >= total) return;
    int tok = idx >> tokshift;
    int rem = idx & ((1 << tokshift) - 1);
    int h = rem >> 6, j = rem & 63;
    int s = tok & 2047;
    size_t a = ((size_t)tok * H + h) * 128 + 2 * j;
    u32 v = *(u32*)(buf + a);
    float re = bf2f((u16)(v & 0xffff));
    float im = bf2f((u16)(v >> 16));
    float c = fc[s * 64 + j], sn = fs[s * 64 + j];
    *(u32*)(buf + a) = pk2bf((re * c - im * sn) * oscale,
                             (re * sn + im * c) * oscale);
}

// ---------------- fused QKV GEMM: A[4096][2048] * WqkvT[4096][2048] ----------------
__global__ __launch_bounds__(256) void gemm_qkv(const u16* __restrict__ A,
                                                const u16* __restrict__ BT,
                                                u16* __restrict__ Qo,
                                                u16* __restrict__ Ko,
                                                u16* __restrict__ Vo) {
    __shared__ u16 As[128 * 32];
    __shared__ u16 Bs[128 * 32];
    const int tid = threadIdx.x;
    const int w = tid >> 6, l = tid & 63;
    const int m0 = blockIdx.y * 128, n0 = blockIdx.x * 128;
    const int wr = w >> 1, wc = w & 1;
    const int l15 = l & 15, lh = l >> 4;

    const f32x4 fz = {0.f, 0.f, 0.f, 0.f};
    f32x4 acc[4][4];
#pragma unroll
    for (int m = 0; m < 4; m++)
#pragma unroll
        for (int n = 0; n < 4; n++) acc[m][n] = fz;

    const int rowA = w * 32 + (l >> 2);
    const int colb = (l & 3) * 8;

    for (int k0 = 0; k0 < 2048; k0 += 32) {
        __syncthreads();
#pragma unroll
        for (int c = 0; c < 2; c++) {
            gload_lds16(A  + (size_t)(m0 + rowA + c * 16) * 2048 + k0 + colb,
                        &As[w * 1024 + c * 512]);
            gload_lds16(BT + (size_t)(n0 + rowA + c * 16) * 2048 + k0 + colb,
                        &Bs[w * 1024 + c * 512]);
        }
        __syncthreads();
        short8 af[4], bfr[4];
#pragma unroll
        for (int m = 0; m < 4; m++)
            af[m] = *(const short8*)&As[(wr * 64 + m * 16 + l15) * 32 + lh * 8];
#pragma unroll
        for (int n = 0; n < 4; n++)
            bfr[n] = *(const short8*)&Bs[(wc * 64 + n * 16 + l15) * 32 + lh * 8];
#pragma unroll
        for (int m = 0; m < 4; m++)
#pragma unroll
            for (int n = 0; n < 4; n++)
                acc[m][n] = mfma16(af[m], bfr[n], acc[m][n]);
    }

    const int rbase = m0 + wr * 64 + lh * 4;
    const int cloc = wc * 64 + l15;

    if (blockIdx.x < 16) {            // Q region
        const int cbase = n0 + cloc;
#pragma unroll
        for (int m = 0; m < 4; m++)
#pragma unroll
            for (int j = 0; j < 4; j++) {
                size_t ro = (size_t)(rbase + m * 16 + j) * 2048 + cbase;
#pragma unroll
                for (int n = 0; n < 4; n++)
                    Qo[ro + n * 16] = f2bf(acc[m][n][j]);
            }
    } else if (blockIdx.x < 24) {     // K region
        const int cbase = (n0 - 2048) + cloc;
#pragma unroll
        for (int m = 0; m < 4; m++)
#pragma unroll
            for (int j = 0; j < 4; j++) {
                size_t ro = (size_t)(rbase + m * 16 + j) * 1024 + cbase;
#pragma unroll
                for (int n = 0; n < 4; n++)
                    Ko[ro + n * 16] = f2bf(acc[m][n][j]);
            }
    } else {                          // V region -> V^T[b][h2][d][s]
        const int cbase = (n0 - 3072) + cloc;
#pragma unroll
        for (int m = 0; m < 4; m++)
#pragma unroll
            for (int n = 0; n < 4; n++) {
                int r = rbase + m * 16;
                int c = cbase + n * 16;
                int bb = r >> 11, ss = r & 2047;
                int h2 = c >> 7, d = c & 127;
                uint2 v;
                v.x = pk2bf(acc[m][n][0], acc[m][n][1]);
                v.y = pk2bf(acc[m][n][2], acc[m][n][3]);
                *(uint2*)(Vo + (size_t)((bb * 8 + h2) * 128 + d) * 2048 + ss) = v;
            }
    }
}

// ---------------- m97-style bf16 GEMM, f32 out (Wo GEMM) ----------------
__global__ __launch_bounds__(256) void gemm_wo(const u16* __restrict__ A,
                                               const u16* __restrict__ BT,
                                               float* __restrict__ Of,
                                               int M, int N, int K) {
    __shared__ u16 As[128 * 32];
    __shared__ u16 Bs[128 * 32];
    const int tid = threadIdx.x;
    const int w = tid >> 6, l = tid & 63;
    const int m0 = blockIdx.y * 128, n0 = blockIdx.x * 128;
    const int wr = w >> 1, wc = w & 1;
    const int l15 = l & 15, lh = l >> 4;

    const f32x4 fz = {0.f, 0.f, 0.f, 0.f};
    f32x4 acc[4][4];
#pragma unroll
    for (int m = 0; m < 4; m++)
#pragma unroll
        for (int n = 0; n < 4; n++) acc[m][n] = fz;

    const int rowA = w * 32 + (l >> 2);
    const int colb = (l & 3) * 8;

    for (int k0 = 0; k0 < K; k0 += 32) {
        __syncthreads();
#pragma unroll
        for (int c = 0; c < 2; c++) {
            gload_lds16(A  + (size_t)(m0 + rowA + c * 16) * K + k0 + colb,
                        &As[w * 1024 + c * 512]);
            gload_lds16(BT + (size_t)(n0 + rowA + c * 16) * K + k0 + colb,
                        &Bs[w * 1024 + c * 512]);
        }
        __syncthreads();
        short8 af[4], bfr[4];
#pragma unroll
        for (int m = 0; m < 4; m++)
            af[m] = *(const short8*)&As[(wr * 64 + m * 16 + l15) * 32 + lh * 8];
#pragma unroll
        for (int n = 0; n < 4; n++)
            bfr[n] = *(const short8*)&Bs[(wc * 64 + n * 16 + l15) * 32 + lh * 8];
#pragma unroll
        for (int m = 0; m < 4; m++)
#pragma unroll
            for (int n = 0; n < 4; n++)
                acc[m][n] = mfma16(af[m], bfr[n], acc[m][n]);
    }

    const int rbase = m0 + wr * 64 + lh * 4;
    const int cbase = n0 + wc * 64 + l15;
#pragma unroll
    for (int m = 0; m < 4; m++)
#pragma unroll
        for (int j = 0; j < 4; j++) {
            size_t ro = (size_t)(rbase + m * 16 + j) * N + cbase;
#pragma unroll
            for (int n = 0; n < 4; n++)
                Of[ro + n * 16] = acc[m][n][j];
        }
}

// ---------------- flash attention (non-causal, GQA) ----------------
// grid (16 qtiles of 128 rows, 32 b*h); block 512 = 8 waves; wave owns 16 q rows.
// K/V double-buffered, staged by global_load_lds with pre-swizzled SOURCE
// (linear LDS dest, m173 pattern); one __syncthreads per tile.
// Softmax in exp2 domain (Q pre-scaled by log2e/sqrt(128)); defer-max THR=8;
// lane-local lsum accumulation, cross-lane reduced once in epilogue.
__global__ __launch_bounds__(512, 4) void attn_kernel(const u16* __restrict__ Q,
                                                      const u16* __restrict__ Kg,
                                                      const u16* __restrict__ Vg,
                                                      u16* __restrict__ O) {
    __shared__ __align__(16) u16 Ks[2][8192];  // [buf][key 64][128] swizzled
    __shared__ __align__(16) u16 Vs[2][8192];  // [buf][d 128][64]  swizzled (V^T)
    __shared__ __align__(16) u16 Ps[8][1024];  // per-wave P [q16][k64] swizzled
    const int tid = threadIdx.x;
    const int w = tid >> 6, l = tid & 63;
    const int qt = blockIdx.x, bh = blockIdx.y;
    const int b = bh >> 4, h = bh & 15, h2 = h >> 1;
    const int l15 = l & 15, lh = l >> 4;

    char* KsB = (char*)&Ks[0][0];
    char* VsB = (char*)&Vs[0][0];
    char* PsB = (char*)&Ps[w][0];

    // staging geometry: block stages K tile (16KB) + V tile (16KB) in 2 issues each
    const char* Kbase = (const char*)Kg + (size_t)b * 2048 * 2048 + h2 * 256;
    const char* Vbase = (const char*)Vg + (size_t)(b * 8 + h2) * 128 * 4096;
    const int X0 = tid * 16, X1 = 8192 + tid * 16;
    const int kr0 = X0 >> 8, kc0 = (X0 & 255) ^ ((kr0 & 7) << 4);
    const int kr1 = X1 >> 8, kc1 = (X1 & 255) ^ ((kr1 & 7) << 4);
    const int vd0 = X0 >> 7, vc0 = (X0 & 127) ^ ((vd0 & 7) << 4);
    const int vd1 = X1 >> 7, vc1 = (X1 & 127) ^ ((vd1 & 7) << 4);
    const int wb = w << 10;   // wave-uniform LDS dest base (bytes)

#define STAGE(t, pb) do {                                              \
        const char* Kt = Kbase + (size_t)(t) * 131072;                 \
        const char* Vt = Vbase + (t) * 128;                            \
        char* kd = KsB + (pb) * 16384;                                 \
        char* vd = VsB + (pb) * 16384;                                 \
        gload_lds16(Kt + kr0 * 2048 + kc0, kd + wb);                   \
        gload_lds16(Kt + kr1 * 2048 + kc1, kd + 8192 + wb);            \
        gload_lds16(Vt + vd0 * 4096 + vc0, vd + wb);                   \
        gload_lds16(Vt + vd1 * 4096 + vc1, vd + 8192 + wb);            \
    } while (0)

    // Q fragments (pre-scaled by log2e/sqrt(128) in rope); A-operand, row = l15
    short8 qf[4];
    {
        const u16* qp = Q + ((size_t)(b * 2048 + qt * 128 + w * 16 + l15)) * 2048
                          + h * 128 + lh * 8;
#pragma unroll
        for (int ks = 0; ks < 4; ks++) qf[ks] = *(const short8*)(qp + ks * 32);
    }

    const f32x4 fz = {0.f, 0.f, 0.f, 0.f};
    f32x4 o[8];
#pragma unroll
    for (int n = 0; n < 8; n++) o[n] = fz;
    float mrow[4] = {-1e30f, -1e30f, -1e30f, -1e30f};
    float lsum[4] = {0.f, 0.f, 0.f, 0.f};   // lane-local partial sums

    STAGE(0, 0);

    for (int t = 0; t < 32; t++) {
        __syncthreads();                 // drains vmcnt(0): stage(t) landed
        const int pb = t & 1;
        if (t < 31) STAGE(t + 1, pb ^ 1);
        const char* kc = KsB + pb * 16384;
        const char* vc = VsB + pb * 16384;
        const int swz = (l15 & 7) << 4;

        // S = Q·K^T: s[ct][r] = S[q = lh*4+r][key = ct*16+l15] (log2 domain)
        f32x4 s[4];
#pragma unroll
        for (int ct = 0; ct < 4; ct++) {
            s[ct] = fz;
#pragma unroll
            for (int ks = 0; ks < 4; ks++) {
                short8 kf = *(const short8*)(kc + ((ct * 16 + l15) << 8)
                                                + ((ks * 64 + lh * 16) ^ swz));
                s[ct] = mfma16(qf[ks], kf, s[ct]);
            }
        }

        // defer-max online softmax; mrow stays uniform across each lh-group
        float pl[4];
#pragma unroll
        for (int r = 0; r < 4; r++)
            pl[r] = fmaxf(fmaxf(s[0][r], s[1][r]), fmaxf(s[2][r], s[3][r]));
        bool grow = (pl[0] > mrow[0] + 8.f) || (pl[1] > mrow[1] + 8.f) ||
                    (pl[2] > mrow[2] + 8.f) || (pl[3] > mrow[3] + 8.f);
        if (__any(grow)) {
#pragma unroll
            for (int r = 0; r < 4; r++) {
                float mx = pl[r];
                mx = fmaxf(mx, __shfl_xor(mx, 1));
                mx = fmaxf(mx, __shfl_xor(mx, 2));
                mx = fmaxf(mx, __shfl_xor(mx, 4));
                mx = fmaxf(mx, __shfl_xor(mx, 8));
                float mnew = fmaxf(mrow[r], mx);
                float fsc = exp2f(mrow[r] - mnew);
                mrow[r] = mnew;
                lsum[r] *= fsc;
#pragma unroll
                for (int n = 0; n < 8; n++) o[n][r] *= fsc;
            }
        }
#pragma unroll
        for (int r = 0; r < 4; r++) {
            float p0 = exp2f(s[0][r] - mrow[r]);
            float p1 = exp2f(s[1][r] - mrow[r]);
            float p2 = exp2f(s[2][r] - mrow[r]);
            float p3 = exp2f(s[3][r] - mrow[r]);
            lsum[r] += (p0 + p1) + (p2 + p3);      // lane-local, reduced at end
            // P[q = lh*4+r][key = ct*16+l15]; swizzle byte ^= ((row&7)<<4)
            const int rw = lh * 4 + r;
            const int rb = rw << 7;
            const int sw = (rw & 7) << 4;
            const int cb2 = l15 << 1;
            // round-half-up bf16 (2 VALU/value), ds_write_b16
            *(u16*)(PsB + (rb + (( 0 + cb2) ^ sw))) =
                (u16)((__float_as_uint(p0) + 0x8000u) >> 16);
            *(u16*)(PsB + (rb + ((32 + cb2) ^ sw))) =
                (u16)((__float_as_uint(p1) + 0x8000u) >> 16);
            *(u16*)(PsB + (rb + ((64 + cb2) ^ sw))) =
                (u16)((__float_as_uint(p2) + 0x8000u) >> 16);
            *(u16*)(PsB + (rb + ((96 + cb2) ^ sw))) =
                (u16)((__float_as_uint(p3) + 0x8000u) >> 16);
        }

        // PV: o[q][d] += P[q][k] * V^T[d][k]   (P-read row = l15, same swizzle)
#pragma unroll
        for (int ks2 = 0; ks2 < 2; ks2++) {
            short8 pf = *(const short8*)(PsB + ((l15 << 7)
                                + ((ks2 * 64 + lh * 16) ^ swz)));
#pragma unroll
            for (int n = 0; n < 8; n++) {
                short8 vf = *(const short8*)(vc + (((n * 16 + l15) << 7)
                                                  + ((ks2 * 64 + lh * 16) ^ swz)));
                o[n] = mfma16(pf, vf, o[n]);
            }
        }
    }

    const size_t ob = ((size_t)(b * 2048 + qt * 128 + w * 16 + lh * 4)) * 2048
                      + h * 128 + l15;
#pragma unroll
    for (int r = 0; r < 4; r++) {
        float ls = lsum[r];
        ls += __shfl_xor(ls, 1);
        ls += __shfl_xor(ls, 2);
        ls += __shfl_xor(ls, 4);
        ls += __shfl_xor(ls, 8);
        float li = 1.0f / ls;
#pragma unroll
        for (int n = 0; n < 8; n++)
            O[ob + (size_t)r * 2048 + n * 16] = f2bf(o[n][r] * li);
    }
#undef STAGE
}

// ---------------- launch ----------------
extern "C" void kernel_launch(void* const* d_in, const int* in_sizes, int n_in,
                              void* d_out, int out_size, void* d_ws, size_t ws_size,
                              hipStream_t stream) {
    const float* x  = (const float*)d_in[0];
    const float* Wq = (const float*)d_in[1];
    const float* Wk = (const float*)d_in[2];
    const float* Wv = (const float*)d_in[3];
    const float* Wo = (const float*)d_in[4];
    const float* fc = (const float*)d_in[5];
    const float* fs = (const float*)d_in[6];
    float* out = (float*)d_out;

    uint8_t* ws = (uint8_t*)d_ws;
    u16* xb   = (u16*)(ws + 0);          // 16.8 MB  (aliased as attn_out later)
    u16* wqkv = (u16*)(ws + 16777216);   // 16.8 MB: wqT | wkT | wvT contiguous
    u16* wqT  = (u16*)(ws + 16777216);
    u16* wkT  = (u16*)(ws + 25165824);
    u16* wvT  = (u16*)(ws + 29360128);
    u16* woT  = (u16*)(ws + 33554432);   // 8.4 MB
    u16* qb   = (u16*)(ws + 41943040);   // 16.8 MB
    u16* kb   = (u16*)(ws + 58720256);   // 8.4 MB
    u16* vT   = (u16*)(ws + 67108864);   // 8.4 MB   total 75.5 MB
    u16* ao   = xb;                      // alias: x_bf16 dead after QKV gemm

    cvt_x<<<dim3(8192), dim3(256), 0, stream>>>(x, xb, 2097152);
    transpose_cvt<<<dim3(32, 32), dim3(256), 0, stream>>>(Wq, wqT, 2048, 2048);
    transpose_cvt<<<dim3(16, 32), dim3(256), 0, stream>>>(Wk, wkT, 2048, 1024);
    transpose_cvt<<<dim3(16, 32), dim3(256), 0, stream>>>(Wv, wvT, 2048, 1024);
    transpose_cvt<<<dim3(32, 32), dim3(256), 0, stream>>>(Wo, woT, 2048, 2048);

    gemm_qkv<<<dim3(32, 32), dim3(256), 0, stream>>>(xb, wqkv, qb, kb, vT);

    // Q carries (1/sqrt(128)) * log2(e) so softmax runs in exp2 domain
    rope_kernel<<<dim3(16384), dim3(256), 0, stream>>>(qb, fc, fs, 16, 10, 4194304,
                                                       0.12751742987f);
    rope_kernel<<<dim3(8192),  dim3(256), 0, stream>>>(kb, fc, fs, 8, 9, 2097152, 1.0f);

    attn_kernel<<<dim3(16, 32), dim3(512), 0, stream>>>(qb, kb, vT, ao);

    gemm_wo<<<dim3(16, 32), dim3(256), 0, stream>>>(ao, woT, out, 4096, 2048, 2048);
}

// Round 6
// 265.265 us; speedup vs baseline: 1.6861x; 1.1047x over previous
//
#include <hip/hip_runtime.h>
#include <stdint.h>

#define DI __device__ __forceinline__

typedef unsigned short u16;
typedef unsigned int   u32;
typedef __attribute__((ext_vector_type(8))) short short8;
typedef __attribute__((ext_vector_type(4))) float f32x4;

// ---- constants (problem shape hardcoded) ----
// B=2, S=2048, HID=2048, HQ=16, HKV=8, D=128

DI u16 f2bf(float f) {
    u32 u = __float_as_uint(f);
    u32 r = u + 0x7fff + ((u >> 16) & 1);   // RNE
    return (u16)(r >> 16);
}
DI u32 pk2bf(float a, float b) {
    return (u32)f2bf(a) | ((u32)f2bf(b) << 16);
}
DI float bf2f(u16 h) { return __uint_as_float(((u32)h) << 16); }

DI f32x4 mfma16(short8 a, short8 b, f32x4 c) {
    return __builtin_amdgcn_mfma_f32_16x16x32_bf16(a, b, c, 0, 0, 0);
}

DI void gload_lds16(const void* g, void* l) {
    __builtin_amdgcn_global_load_lds(
        (const __attribute__((address_space(1))) void*)g,
        (__attribute__((address_space(3))) void*)l, 16, 0, 0);
}

// ---------------- convert x f32 -> bf16 ----------------
__global__ __launch_bounds__(256) void cvt_x(const float* __restrict__ x,
                                             u16* __restrict__ o, int n4) {
    int i = blockIdx.x * 256 + threadIdx.x;
    if (i >= n4) return;
    float4 v = *(const float4*)(x + (size_t)i * 4);
    uint2 p; p.x = pk2bf(v.x, v.y); p.y = pk2bf(v.z, v.w);
    *(uint2*)(o + (size_t)i * 4) = p;
}

// ---------------- W [K][N] f32 -> WT [N][K] bf16 ----------------
__global__ __launch_bounds__(256) void transpose_cvt(const float* __restrict__ W,
                                                     u16* __restrict__ WT,
                                                     int K, int N) {
    __shared__ u16 tl[64][65];
    int tx = threadIdx.x & 15, ty = threadIdx.x >> 4;
    int tc = blockIdx.x * 64, tr = blockIdx.y * 64;
#pragma unroll
    for (int i = 0; i < 4; i++) {
        int r = tr + ty + i * 16;
        float4 v = *(const float4*)&W[(size_t)r * N + tc + tx * 4];
        tl[tx*4+0][ty+i*16] = f2bf(v.x);
        tl[tx*4+1][ty+i*16] = f2bf(v.y);
        tl[tx*4+2][ty+i*16] = f2bf(v.z);
        tl[tx*4+3][ty+i*16] = f2bf(v.w);
    }
    __syncthreads();
#pragma unroll
    for (int i = 0; i < 4; i++) {
        int n = tc + ty + i * 16;
        uint2 p;
        p.x = (u32)tl[ty+i*16][tx*4+0] | ((u32)tl[ty+i*16][tx*4+1] << 16);
        p.y = (u32)tl[ty+i*16][tx*4+2] | ((u32)tl[ty+i*16][tx*4+3] << 16);
        *(uint2*)&WT[(size_t)n * K + tr + tx * 4] = p;
    }
}

// ---------------- RoPE in-place on bf16 [tok][H*128], output scaled ----------------
__global__ __launch_bounds__(256) void rope_kernel(u16* __restrict__ buf,
                                                   const float* __restrict__ fc,
                                                   const float* __restrict__ fs,
                                                   int H, int tokshift, int total,
                                                   float oscale) {
    int idx = blockIdx.x * 256 + threadIdx.x;
    if (idx >= total) return;
    int tok = idx >> tokshift;
    int rem = idx & ((1 << tokshift) - 1);
    int h = rem >> 6, j = rem & 63;
    int s = tok & 2047;
    size_t a = ((size_t)tok * H + h) * 128 + 2 * j;
    u32 v = *(u32*)(buf + a);
    float re = bf2f((u16)(v & 0xffff));
    float im = bf2f((u16)(v >> 16));
    float c = fc[s * 64 + j], sn = fs[s * 64 + j];
    *(u32*)(buf + a) = pk2bf((re * c - im * sn) * oscale,
                             (re * sn + im * c) * oscale);
}

// ---------------- 8-phase 256^2 QKV GEMM (T2+T3+T4+T5, m201 template) --------
// A[4096][2048] * WqkvT[4096][2048]^T. 256 blocks, 512 thr = 8 waves (2M x 4N).
// LDS 128KB: [buf2][A|B][half2][128][64]bf16, st_16x32 swizzled via
// pre-swizzled global source (linear gload_lds dest) + lane-const read XOR.
// 4 phases/K-tile; counted vmcnt(2) at tile boundary (never 0).
__global__ __launch_bounds__(512) void gemm_qkv8(const u16* __restrict__ A,
                                                 const u16* __restrict__ BT,
                                                 u16* __restrict__ Qo,
                                                 u16* __restrict__ Ko,
                                                 u16* __restrict__ Vo) {
    __shared__ __align__(16) u16 SM[65536];   // 128 KB
    char* smb = (char*)SM;
    const int tid = threadIdx.x;
    const int w = tid >> 6, l = tid & 63;
    const int l15 = l & 15, lh = l >> 4;
    const int wr = w >> 2, wc = w & 3;

    // XCD-aware bijective swizzle (nwg=256, 256%8==0)
    const int bid = blockIdx.x;
    const int sw = (bid & 7) * 32 + (bid >> 3);
    const int bx = sw & 15, by = sw >> 4;

    const char* Ag = (const char*)A  + (size_t)(by * 256) * 4096;
    const char* Bg = (const char*)BT + (size_t)(bx * 256) * 4096;

    // staging: thread's linear LDS dest X = tid*16 (+8192); source pre-swizzled
    const int r0 = tid >> 3;                                   // row in half
    const int c0 = ((tid & 7) << 4) ^ (((tid >> 5) & 1) << 5); // byte in row
    const int wb = w << 10;

#define STG_A(tt, bb, hh) do {                                              \
        const char* s_ = Ag + (size_t)((hh) * 128 + r0) * 4096 + (tt) * 128 + c0; \
        char* d_ = smb + (bb) * 65536 + (hh) * 16384 + wb;                  \
        gload_lds16(s_, d_);                                                \
        gload_lds16(s_ + (size_t)64 * 4096, d_ + 8192);                     \
    } while (0)
#define STG_B(tt, bb, hh) do {                                              \
        const char* s_ = Bg + (size_t)((hh) * 128 + r0) * 4096 + (tt) * 128 + c0; \
        char* d_ = smb + (bb) * 65536 + 32768 + (hh) * 16384 + wb;          \
        gload_lds16(s_, d_);                                                \
        gload_lds16(s_ + (size_t)64 * 4096, d_ + 8192);                     \
    } while (0)

    // read-side lane-constant swizzled base (within a half-tile)
    const int aoff = l15 * 128 + ((lh * 16) ^ (((l15 >> 2) & 1) << 5));

    const f32x4 fz = {0.f, 0.f, 0.f, 0.f};
    f32x4 acc[8][4];
#pragma unroll
    for (int m = 0; m < 8; m++)
#pragma unroll
        for (int n = 0; n < 4; n++) acc[m][n] = fz;

    // prologue: tile0 fully + A-half0 of tile1; counted wait
    STG_A(0, 0, 0); STG_A(0, 0, 1); STG_B(0, 0, 0); STG_B(0, 0, 1);
    STG_A(1, 1, 0);
    asm volatile("s_waitcnt vmcnt(2)" ::: "memory");
    __builtin_amdgcn_s_barrier();

    for (int t = 0; t < 32; ++t) {
        const int cur = t & 1;
        const int t1 = t + 1 < 32 ? t + 1 : 31;
        const int t2 = t + 2 < 32 ? t + 2 : 31;
        const char* Ab = smb + cur * 65536 + wr * 16384 + aoff;
        const char* Bb = smb + cur * 65536 + 32768 + (wc >> 1) * 16384
                         + (wc & 1) * 8192 + aoff;
        short8 aF[4][2], bF[4][2];

        // ---- phase 1: stage A1(t+1); read A m0-3 + B n0-1; MFMA q0
        STG_A(t1, cur ^ 1, 1);
#pragma unroll
        for (int m = 0; m < 4; m++) {
            aF[m][0] = *(const short8*)(Ab + m * 2048);
            aF[m][1] = *(const short8*)(Ab + m * 2048 + 64);
        }
#pragma unroll
        for (int n = 0; n < 2; n++) {
            bF[n][0] = *(const short8*)(Bb + n * 2048);
            bF[n][1] = *(const short8*)(Bb + n * 2048 + 64);
        }
        __builtin_amdgcn_s_setprio(1);
#pragma unroll
        for (int m = 0; m < 4; m++)
#pragma unroll
            for (int n = 0; n < 2; n++) {
                acc[m][n] = mfma16(aF[m][0], bF[n][0], acc[m][n]);
                acc[m][n] = mfma16(aF[m][1], bF[n][1], acc[m][n]);
            }
        __builtin_amdgcn_s_setprio(0);
        __builtin_amdgcn_s_barrier();

        // ---- phase 2: stage B0(t+1); read B n2-3; MFMA q1
        STG_B(t1, cur ^ 1, 0);
#pragma unroll
        for (int n = 2; n < 4; n++) {
            bF[n][0] = *(const short8*)(Bb + n * 2048);
            bF[n][1] = *(const short8*)(Bb + n * 2048 + 64);
        }
        __builtin_amdgcn_s_setprio(1);
#pragma unroll
        for (int m = 0; m < 4; m++)
#pragma unroll
            for (int n = 2; n < 4; n++) {
                acc[m][n] = mfma16(aF[m][0], bF[n][0], acc[m][n]);
                acc[m][n] = mfma16(aF[m][1], bF[n][1], acc[m][n]);
            }
        __builtin_amdgcn_s_setprio(0);
        __builtin_amdgcn_s_barrier();

        // ---- phase 3: stage B1(t+1); read A m4-7; MFMA q2
        STG_B(t1, cur ^ 1, 1);
#pragma unroll
        for (int m = 0; m < 4; m++) {
            aF[m][0] = *(const short8*)(Ab + (m + 4) * 2048);
            aF[m][1] = *(const short8*)(Ab + (m + 4) * 2048 + 64);
        }
        __builtin_amdgcn_s_setprio(1);
#pragma unroll
        for (int m = 0; m < 4; m++)
#pragma unroll
            for (int n = 0; n < 2; n++) {
                acc[m + 4][n] = mfma16(aF[m][0], bF[n][0], acc[m + 4][n]);
                acc[m + 4][n] = mfma16(aF[m][1], bF[n][1], acc[m + 4][n]);
            }
        __builtin_amdgcn_s_setprio(0);
        __builtin_amdgcn_s_barrier();

        // ---- phase 4: stage A0(t+2) into buf cur (freed after ph3); MFMA q3
        STG_A(t2, cur, 0);
        __builtin_amdgcn_s_setprio(1);
#pragma unroll
        for (int m = 0; m < 4; m++)
#pragma unroll
            for (int n = 2; n < 4; n++) {
                acc[m + 4][n] = mfma16(aF[m][0], bF[n][0], acc[m + 4][n]);
                acc[m + 4][n] = mfma16(aF[m][1], bF[n][1], acc[m + 4][n]);
            }
        __builtin_amdgcn_s_setprio(0);
        asm volatile("s_waitcnt vmcnt(2)" ::: "memory");   // t+1 halves landed
        __builtin_amdgcn_s_barrier();
    }
#undef STG_A
#undef STG_B

    // epilogue: rows = tokens, cols = QKV features
    const int rbase = by * 256 + wr * 128 + lh * 4;
    const int cbase = bx * 256 + wc * 64 + l15;
    if (bx < 8) {                       // Q [tok][2048]
#pragma unroll
        for (int m = 0; m < 8; m++)
#pragma unroll
            for (int j = 0; j < 4; j++) {
                size_t ro = (size_t)(rbase + m * 16 + j) * 2048 + cbase;
#pragma unroll
                for (int n = 0; n < 4; n++)
                    Qo[ro + n * 16] = f2bf(acc[m][n][j]);
            }
    } else if (bx < 12) {               // K [tok][1024]
        const int ck = cbase - 2048;
#pragma unroll
        for (int m = 0; m < 8; m++)
#pragma unroll
            for (int j = 0; j < 4; j++) {
                size_t ro = (size_t)(rbase + m * 16 + j) * 1024 + ck;
#pragma unroll
                for (int n = 0; n < 4; n++)
                    Ko[ro + n * 16] = f2bf(acc[m][n][j]);
            }
    } else {                            // V -> V^T[b][h2][d][s]
#pragma unroll
        for (int m = 0; m < 8; m++)
#pragma unroll
            for (int n = 0; n < 4; n++) {
                int tok = rbase + m * 16;
                int c = cbase + n * 16 - 3072;
                int bb2 = tok >> 11, ss = tok & 2047;
                int h2 = c >> 7, d = c & 127;
                uint2 v;
                v.x = pk2bf(acc[m][n][0], acc[m][n][1]);
                v.y = pk2bf(acc[m][n][2], acc[m][n][3]);
                *(uint2*)(Vo + (size_t)((bb2 * 8 + h2) * 128 + d) * 2048 + ss) = v;
            }
    }
}

// ---------------- m97-style bf16 GEMM, f32 out (Wo GEMM) ----------------
__global__ __launch_bounds__(256) void gemm_wo(const u16* __restrict__ A,
                                               const u16* __restrict__ BT,
                                               float* __restrict__ Of,
                                               int M, int N, int K) {
    __shared__ u16 As[128 * 32];
    __shared__ u16 Bs[128 * 32];
    const int tid = threadIdx.x;
    const int w = tid >> 6, l = tid & 63;
    const int m0 = blockIdx.y * 128, n0 = blockIdx.x * 128;
    const int wr = w >> 1, wc = w & 1;
    const int l15 = l & 15, lh = l >> 4;

    const f32x4 fz = {0.f, 0.f, 0.f, 0.f};
    f32x4 acc[4][4];
#pragma unroll
    for (int m = 0; m < 4; m++)
#pragma unroll
        for (int n = 0; n < 4; n++) acc[m][n] = fz;

    const int rowA = w * 32 + (l >> 2);
    const int colb = (l & 3) * 8;

    for (int k0 = 0; k0 < K; k0 += 32) {
        __syncthreads();
#pragma unroll
        for (int c = 0; c < 2; c++) {
            gload_lds16(A  + (size_t)(m0 + rowA + c * 16) * K + k0 + colb,
                        &As[w * 1024 + c * 512]);
            gload_lds16(BT + (size_t)(n0 + rowA + c * 16) * K + k0 + colb,
                        &Bs[w * 1024 + c * 512]);
        }
        __syncthreads();
        short8 af[4], bfr[4];
#pragma unroll
        for (int m = 0; m < 4; m++)
            af[m] = *(const short8*)&As[(wr * 64 + m * 16 + l15) * 32 + lh * 8];
#pragma unroll
        for (int n = 0; n < 4; n++)
            bfr[n] = *(const short8*)&Bs[(wc * 64 + n * 16 + l15) * 32 + lh * 8];
#pragma unroll
        for (int m = 0; m < 4; m++)
#pragma unroll
            for (int n = 0; n < 4; n++)
                acc[m][n] = mfma16(af[m], bfr[n], acc[m][n]);
    }

    const int rbase = m0 + wr * 64 + lh * 4;
    const int cbase = n0 + wc * 64 + l15;
#pragma unroll
    for (int m = 0; m < 4; m++)
#pragma unroll
        for (int j = 0; j < 4; j++) {
            size_t ro = (size_t)(rbase + m * 16 + j) * N + cbase;
#pragma unroll
            for (int n = 0; n < 4; n++)
                Of[ro + n * 16] = acc[m][n][j];
        }
}

// ---------------- flash attention (non-causal, GQA) ----------------
__global__ __launch_bounds__(512, 4) void attn_kernel(const u16* __restrict__ Q,
                                                      const u16* __restrict__ Kg,
                                                      const u16* __restrict__ Vg,
                                                      u16* __restrict__ O) {
    __shared__ __align__(16) u16 Ks[2][8192];
    __shared__ __align__(16) u16 Vs[2][8192];
    __shared__ __align__(16) u16 Ps[8][1024];
    const int tid = threadIdx.x;
    const int w = tid >> 6, l = tid & 63;
    const int qt = blockIdx.x, bh = blockIdx.y;
    const int b = bh >> 4, h = bh & 15, h2 = h >> 1;
    const int l15 = l & 15, lh = l >> 4;

    char* KsB = (char*)&Ks[0][0];
    char* VsB = (char*)&Vs[0][0];
    char* PsB = (char*)&Ps[w][0];

    const char* Kbase = (const char*)Kg + (size_t)b * 2048 * 2048 + h2 * 256;
    const char* Vbase = (const char*)Vg + (size_t)(b * 8 + h2) * 128 * 4096;
    const int X0 = tid * 16, X1 = 8192 + tid * 16;
    const int kr0 = X0 >> 8, kc0 = (X0 & 255) ^ ((kr0 & 7) << 4);
    const int kr1 = X1 >> 8, kc1 = (X1 & 255) ^ ((kr1 & 7) << 4);
    const int vd0 = X0 >> 7, vc0 = (X0 & 127) ^ ((vd0 & 7) << 4);
    const int vd1 = X1 >> 7, vc1 = (X1 & 127) ^ ((vd1 & 7) << 4);
    const int wb = w << 10;

#define STAGE(t, pb) do {                                              \
        const char* Kt = Kbase + (size_t)(t) * 131072;                 \
        const char* Vt = Vbase + (t) * 128;                            \
        char* kd = KsB + (pb) * 16384;                                 \
        char* vd = VsB + (pb) * 16384;                                 \
        gload_lds16(Kt + kr0 * 2048 + kc0, kd + wb);                   \
        gload_lds16(Kt + kr1 * 2048 + kc1, kd + 8192 + wb);            \
        gload_lds16(Vt + vd0 * 4096 + vc0, vd + wb);                   \
        gload_lds16(Vt + vd1 * 4096 + vc1, vd + 8192 + wb);            \
    } while (0)

    short8 qf[4];
    {
        const u16* qp = Q + ((size_t)(b * 2048 + qt * 128 + w * 16 + l15)) * 2048
                          + h * 128 + lh * 8;
#pragma unroll
        for (int ks = 0; ks < 4; ks++) qf[ks] = *(const short8*)(qp + ks * 32);
    }

    const f32x4 fz = {0.f, 0.f, 0.f, 0.f};
    f32x4 o[8];
#pragma unroll
    for (int n = 0; n < 8; n++) o[n] = fz;
    float mrow[4] = {-1e30f, -1e30f, -1e30f, -1e30f};
    float lsum[4] = {0.f, 0.f, 0.f, 0.f};

    STAGE(0, 0);

    for (int t = 0; t < 32; t++) {
        __syncthreads();
        const int pb = t & 1;
        if (t < 31) STAGE(t + 1, pb ^ 1);
        const char* kc = KsB + pb * 16384;
        const char* vc = VsB + pb * 16384;
        const int swz = (l15 & 7) << 4;

        f32x4 s[4];
#pragma unroll
        for (int ct = 0; ct < 4; ct++) {
            s[ct] = fz;
#pragma unroll
            for (int ks = 0; ks < 4; ks++) {
                short8 kf = *(const short8*)(kc + ((ct * 16 + l15) << 8)
                                                + ((ks * 64 + lh * 16) ^ swz));
                s[ct] = mfma16(qf[ks], kf, s[ct]);
            }
        }

        float pl[4];
#pragma unroll
        for (int r = 0; r < 4; r++)
            pl[r] = fmaxf(fmaxf(s[0][r], s[1][r]), fmaxf(s[2][r], s[3][r]));
        bool grow = (pl[0] > mrow[0] + 8.f) || (pl[1] > mrow[1] + 8.f) ||
                    (pl[2] > mrow[2] + 8.f) || (pl[3] > mrow[3] + 8.f);
        if (__any(grow)) {
#pragma unroll
            for (int r = 0; r < 4; r++) {
                float mx = pl[r];
                mx = fmaxf(mx, __shfl_xor(mx, 1));
                mx = fmaxf(mx, __shfl_xor(mx, 2));
                mx = fmaxf(mx, __shfl_xor(mx, 4));
                mx = fmaxf(mx, __shfl_xor(mx, 8));
                float mnew = fmaxf(mrow[r], mx);
                float fsc = exp2f(mrow[r] - mnew);
                mrow[r] = mnew;
                lsum[r] *= fsc;
#pragma unroll
                for (int n = 0; n < 8; n++) o[n][r] *= fsc;
            }
        }
#pragma unroll
        for (int r = 0; r < 4; r++) {
            float p0 = exp2f(s[0][r] - mrow[r]);
            float p1 = exp2f(s[1][r] - mrow[r]);
            float p2 = exp2f(s[2][r] - mrow[r]);
            float p3 = exp2f(s[3][r] - mrow[r]);
            lsum[r] += (p0 + p1) + (p2 + p3);
            const int rw = lh * 4 + r;
            const int rb = rw << 7;
            const int sw2 = (rw & 7) << 4;
            const int cb2 = l15 << 1;
            *(u16*)(PsB + (rb + (( 0 + cb2) ^ sw2))) =
                (u16)((__float_as_uint(p0) + 0x8000u) >> 16);
            *(u16*)(PsB + (rb + ((32 + cb2) ^ sw2))) =
                (u16)((__float_as_uint(p1) + 0x8000u) >> 16);
            *(u16*)(PsB + (rb + ((64 + cb2) ^ sw2))) =
                (u16)((__float_as_uint(p2) + 0x8000u) >> 16);
            *(u16*)(PsB + (rb + ((96 + cb2) ^ sw2))) =
                (u16)((__float_as_uint(p3) + 0x8000u) >> 16);
        }

#pragma unroll
        for (int ks2 = 0; ks2 < 2; ks2++) {
            short8 pf = *(const short8*)(PsB + ((l15 << 7)
                                + ((ks2 * 64 + lh * 16) ^ swz)));
#pragma unroll
            for (int n = 0; n < 8; n++) {
                short8 vf = *(const short8*)(vc + (((n * 16 + l15) << 7)
                                                  + ((ks2 * 64 + lh * 16) ^ swz)));
                o[n] = mfma16(pf, vf, o[n]);
            }
        }
    }

    const size_t ob = ((size_t)(b * 2048 + qt * 128 + w * 16 + lh * 4)) * 2048
                      + h * 128 + l15;
#pragma unroll
    for (int r = 0; r < 4; r++) {
        float ls = lsum[r];
        ls += __shfl_xor(ls, 1);
        ls += __shfl_xor(ls, 2);
        ls += __shfl_xor(ls, 4);
        ls += __shfl_xor(ls, 8);
        float li = 1.0f / ls;
#pragma unroll
        for (int n = 0; n < 8; n++)
            O[ob + (size_t)r * 2048 + n * 16] = f2bf(o[n][r] * li);
    }
#undef STAGE
}

// ---------------- launch ----------------
extern "C" void kernel_launch(void* const* d_in, const int* in_sizes, int n_in,
                              void* d_out, int out_size, void* d_ws, size_t ws_size,
                              hipStream_t stream) {
    const float* x  = (const float*)d_in[0];
    const float* Wq = (const float*)d_in[1];
    const float* Wk = (const float*)d_in[2];
    const float* Wv = (const float*)d_in[3];
    const float* Wo = (const float*)d_in[4];
    const float* fc = (const float*)d_in[5];
    const float* fs = (const float*)d_in[6];
    float* out = (float*)d_out;

    uint8_t* ws = (uint8_t*)d_ws;
    u16* xb   = (u16*)(ws + 0);          // 16.8 MB  (aliased as attn_out later)
    u16* wqkv = (u16*)(ws + 16777216);   // 16.8 MB: wqT | wkT | wvT contiguous
    u16* wqT  = (u16*)(ws + 16777216);
    u16* wkT  = (u16*)(ws + 25165824);
    u16* wvT  = (u16*)(ws + 29360128);
    u16* woT  = (u16*)(ws + 33554432);   // 8.4 MB
    u16* qb   = (u16*)(ws + 41943040);   // 16.8 MB
    u16* kb   = (u16*)(ws + 58720256);   // 8.4 MB
    u16* vT   = (u16*)(ws + 67108864);   // 8.4 MB   total 75.5 MB
    u16* ao   = xb;                      // alias: x_bf16 dead after QKV gemm

    cvt_x<<<dim3(8192), dim3(256), 0, stream>>>(x, xb, 2097152);
    transpose_cvt<<<dim3(32, 32), dim3(256), 0, stream>>>(Wq, wqT, 2048, 2048);
    transpose_cvt<<<dim3(16, 32), dim3(256), 0, stream>>>(Wk, wkT, 2048, 1024);
    transpose_cvt<<<dim3(16, 32), dim3(256), 0, stream>>>(Wv, wvT, 2048, 1024);
    transpose_cvt<<<dim3(32, 32), dim3(256), 0, stream>>>(Wo, woT, 2048, 2048);

    gemm_qkv8<<<dim3(256), dim3(512), 0, stream>>>(xb, wqkv, qb, kb, vT);

    // Q carries (1/sqrt(128)) * log2(e) so softmax runs in exp2 domain
    rope_kernel<<<dim3(16384), dim3(256), 0, stream>>>(qb, fc, fs, 16, 10, 4194304,
                                                       0.12751742987f);
    rope_kernel<<<dim3(8192),  dim3(256), 0, stream>>>(kb, fc, fs, 8, 9, 2097152, 1.0f);

    attn_kernel<<<dim3(16, 32), dim3(512), 0, stream>>>(qb, kb, vT, ao);

    gemm_wo<<<dim3(16, 32), dim3(256), 0, stream>>>(ao, woT, out, 4096, 2048, 2048);
}

// Round 7
// 256.015 us; speedup vs baseline: 1.7470x; 1.0361x over previous
//
#include <hip/hip_runtime.h>
#include <stdint.h>

#define DI __device__ __forceinline__

typedef unsigned short u16;
typedef unsigned int   u32;
typedef __attribute__((ext_vector_type(8))) short short8;
typedef __attribute__((ext_vector_type(4))) float f32x4;

// ---- constants (problem shape hardcoded) ----
// B=2, S=2048, HID=2048, HQ=16, HKV=8, D=128

DI u16 f2bf(float f) {
    u32 u = __float_as_uint(f);
    u32 r = u + 0x7fff + ((u >> 16) & 1);   // RNE
    return (u16)(r >> 16);
}
DI u32 pk2bf(float a, float b) {
    return (u32)f2bf(a) | ((u32)f2bf(b) << 16);
}
DI float bf2f(u16 h) { return __uint_as_float(((u32)h) << 16); }

DI f32x4 mfma16(short8 a, short8 b, f32x4 c) {
    return __builtin_amdgcn_mfma_f32_16x16x32_bf16(a, b, c, 0, 0, 0);
}

DI void gload_lds16(const void* g, void* l) {
    __builtin_amdgcn_global_load_lds(
        (const __attribute__((address_space(1))) void*)g,
        (__attribute__((address_space(3))) void*)l, 16, 0, 0);
}

// ---------------- convert x f32 -> bf16 ----------------
__global__ __launch_bounds__(256) void cvt_x(const float* __restrict__ x,
                                             u16* __restrict__ o, int n4) {
    int i = blockIdx.x * 256 + threadIdx.x;
    if (i >= n4) return;
    float4 v = *(const float4*)(x + (size_t)i * 4);
    uint2 p; p.x = pk2bf(v.x, v.y); p.y = pk2bf(v.z, v.w);
    *(uint2*)(o + (size_t)i * 4) = p;
}

// ---------------- all 4 weights: W [K][N] f32 -> WT [N][K] bf16, one launch ----
__global__ __launch_bounds__(256) void transpose_cvt4(const float* __restrict__ W0,
                                                      const float* __restrict__ W1,
                                                      const float* __restrict__ W2,
                                                      const float* __restrict__ W3,
                                                      u16* __restrict__ D0,
                                                      u16* __restrict__ D1,
                                                      u16* __restrict__ D2,
                                                      u16* __restrict__ D3) {
    const float* W; u16* D; int N;
    switch (blockIdx.z) {
        case 0:  W = W0; D = D0; N = 2048; break;
        case 1:  W = W1; D = D1; N = 1024; break;
        case 2:  W = W2; D = D2; N = 1024; break;
        default: W = W3; D = D3; N = 2048; break;
    }
    if ((int)blockIdx.x >= (N >> 6)) return;
    const int K = 2048;
    __shared__ u16 tl[64][65];
    int tx = threadIdx.x & 15, ty = threadIdx.x >> 4;
    int tc = blockIdx.x * 64, tr = blockIdx.y * 64;
#pragma unroll
    for (int i = 0; i < 4; i++) {
        int r = tr + ty + i * 16;
        float4 v = *(const float4*)&W[(size_t)r * N + tc + tx * 4];
        tl[tx*4+0][ty+i*16] = f2bf(v.x);
        tl[tx*4+1][ty+i*16] = f2bf(v.y);
        tl[tx*4+2][ty+i*16] = f2bf(v.z);
        tl[tx*4+3][ty+i*16] = f2bf(v.w);
    }
    __syncthreads();
#pragma unroll
    for (int i = 0; i < 4; i++) {
        int n = tc + ty + i * 16;
        uint2 p;
        p.x = (u32)tl[ty+i*16][tx*4+0] | ((u32)tl[ty+i*16][tx*4+1] << 16);
        p.y = (u32)tl[ty+i*16][tx*4+2] | ((u32)tl[ty+i*16][tx*4+3] << 16);
        *(uint2*)&D[(size_t)n * K + tr + tx * 4] = p;
    }
}

// ---------------- RoPE in-place on bf16 [tok][H*128], output scaled ----------------
__global__ __launch_bounds__(256) void rope_kernel(u16* __restrict__ buf,
                                                   const float* __restrict__ fc,
                                                   const float* __restrict__ fs,
                                                   int H, int tokshift, int total,
                                                   float oscale) {
    int idx = blockIdx.x * 256 + threadIdx.x;
    if (idx >= total) return;
    int tok = idx >> tokshift;
    int rem = idx & ((1 << tokshift) - 1);
    int h = rem >> 6, j = rem & 63;
    int s = tok & 2047;
    size_t a = ((size_t)tok * H + h) * 128 + 2 * j;
    u32 v = *(u32*)(buf + a);
    float re = bf2f((u16)(v & 0xffff));
    float im = bf2f((u16)(v >> 16));
    float c = fc[s * 64 + j], sn = fs[s * 64 + j];
    *(u32*)(buf + a) = pk2bf((re * c - im * sn) * oscale,
                             (re * sn + im * c) * oscale);
}

// ---------------- 8-phase 256^2 QKV GEMM (T2+T3+T4+T5) --------
__global__ __launch_bounds__(512) void gemm_qkv8(const u16* __restrict__ A,
                                                 const u16* __restrict__ BT,
                                                 u16* __restrict__ Qo,
                                                 u16* __restrict__ Ko,
                                                 u16* __restrict__ Vo) {
    __shared__ __align__(16) u16 SM[65536];   // 128 KB
    char* smb = (char*)SM;
    const int tid = threadIdx.x;
    const int w = tid >> 6, l = tid & 63;
    const int l15 = l & 15, lh = l >> 4;
    const int wr = w >> 2, wc = w & 3;

    const int bid = blockIdx.x;
    const int sw = (bid & 7) * 32 + (bid >> 3);
    const int bx = sw & 15, by = sw >> 4;

    const char* Ag = (const char*)A  + (size_t)(by * 256) * 4096;
    const char* Bg = (const char*)BT + (size_t)(bx * 256) * 4096;

    const int r0 = tid >> 3;
    const int c0 = ((tid & 7) << 4) ^ (((tid >> 5) & 1) << 5);
    const int wb = w << 10;

#define STG_A(tt, bb, hh) do {                                              \
        const char* s_ = Ag + (size_t)((hh) * 128 + r0) * 4096 + (tt) * 128 + c0; \
        char* d_ = smb + (bb) * 65536 + (hh) * 16384 + wb;                  \
        gload_lds16(s_, d_);                                                \
        gload_lds16(s_ + (size_t)64 * 4096, d_ + 8192);                     \
    } while (0)
#define STG_B(tt, bb, hh) do {                                              \
        const char* s_ = Bg + (size_t)((hh) * 128 + r0) * 4096 + (tt) * 128 + c0; \
        char* d_ = smb + (bb) * 65536 + 32768 + (hh) * 16384 + wb;          \
        gload_lds16(s_, d_);                                                \
        gload_lds16(s_ + (size_t)64 * 4096, d_ + 8192);                     \
    } while (0)

    const int aoff = l15 * 128 + ((lh * 16) ^ (((l15 >> 2) & 1) << 5));

    const f32x4 fz = {0.f, 0.f, 0.f, 0.f};
    f32x4 acc[8][4];
#pragma unroll
    for (int m = 0; m < 8; m++)
#pragma unroll
        for (int n = 0; n < 4; n++) acc[m][n] = fz;

    STG_A(0, 0, 0); STG_A(0, 0, 1); STG_B(0, 0, 0); STG_B(0, 0, 1);
    STG_A(1, 1, 0);
    asm volatile("s_waitcnt vmcnt(2)" ::: "memory");
    __builtin_amdgcn_s_barrier();

    for (int t = 0; t < 32; ++t) {
        const int cur = t & 1;
        const int t1 = t + 1 < 32 ? t + 1 : 31;
        const int t2 = t + 2 < 32 ? t + 2 : 31;
        const char* Ab = smb + cur * 65536 + wr * 16384 + aoff;
        const char* Bb = smb + cur * 65536 + 32768 + (wc >> 1) * 16384
                         + (wc & 1) * 8192 + aoff;
        short8 aF[4][2], bF[4][2];

        STG_A(t1, cur ^ 1, 1);
#pragma unroll
        for (int m = 0; m < 4; m++) {
            aF[m][0] = *(const short8*)(Ab + m * 2048);
            aF[m][1] = *(const short8*)(Ab + m * 2048 + 64);
        }
#pragma unroll
        for (int n = 0; n < 2; n++) {
            bF[n][0] = *(const short8*)(Bb + n * 2048);
            bF[n][1] = *(const short8*)(Bb + n * 2048 + 64);
        }
        __builtin_amdgcn_s_setprio(1);
#pragma unroll
        for (int m = 0; m < 4; m++)
#pragma unroll
            for (int n = 0; n < 2; n++) {
                acc[m][n] = mfma16(aF[m][0], bF[n][0], acc[m][n]);
                acc[m][n] = mfma16(aF[m][1], bF[n][1], acc[m][n]);
            }
        __builtin_amdgcn_s_setprio(0);
        __builtin_amdgcn_s_barrier();

        STG_B(t1, cur ^ 1, 0);
#pragma unroll
        for (int n = 2; n < 4; n++) {
            bF[n][0] = *(const short8*)(Bb + n * 2048);
            bF[n][1] = *(const short8*)(Bb + n * 2048 + 64);
        }
        __builtin_amdgcn_s_setprio(1);
#pragma unroll
        for (int m = 0; m < 4; m++)
#pragma unroll
            for (int n = 2; n < 4; n++) {
                acc[m][n] = mfma16(aF[m][0], bF[n][0], acc[m][n]);
                acc[m][n] = mfma16(aF[m][1], bF[n][1], acc[m][n]);
            }
        __builtin_amdgcn_s_setprio(0);
        __builtin_amdgcn_s_barrier();

        STG_B(t1, cur ^ 1, 1);
#pragma unroll
        for (int m = 0; m < 4; m++) {
            aF[m][0] = *(const short8*)(Ab + (m + 4) * 2048);
            aF[m][1] = *(const short8*)(Ab + (m + 4) * 2048 + 64);
        }
        __builtin_amdgcn_s_setprio(1);
#pragma unroll
        for (int m = 0; m < 4; m++)
#pragma unroll
            for (int n = 0; n < 2; n++) {
                acc[m + 4][n] = mfma16(aF[m][0], bF[n][0], acc[m + 4][n]);
                acc[m + 4][n] = mfma16(aF[m][1], bF[n][1], acc[m + 4][n]);
            }
        __builtin_amdgcn_s_setprio(0);
        __builtin_amdgcn_s_barrier();

        STG_A(t2, cur, 0);
        __builtin_amdgcn_s_setprio(1);
#pragma unroll
        for (int m = 0; m < 4; m++)
#pragma unroll
            for (int n = 2; n < 4; n++) {
                acc[m + 4][n] = mfma16(aF[m][0], bF[n][0], acc[m + 4][n]);
                acc[m + 4][n] = mfma16(aF[m][1], bF[n][1], acc[m + 4][n]);
            }
        __builtin_amdgcn_s_setprio(0);
        asm volatile("s_waitcnt vmcnt(2)" ::: "memory");
        __builtin_amdgcn_s_barrier();
    }
#undef STG_A
#undef STG_B

    const int rbase = by * 256 + wr * 128 + lh * 4;
    const int cbase = bx * 256 + wc * 64 + l15;
    if (bx < 8) {
#pragma unroll
        for (int m = 0; m < 8; m++)
#pragma unroll
            for (int j = 0; j < 4; j++) {
                size_t ro = (size_t)(rbase + m * 16 + j) * 2048 + cbase;
#pragma unroll
                for (int n = 0; n < 4; n++)
                    Qo[ro + n * 16] = f2bf(acc[m][n][j]);
            }
    } else if (bx < 12) {
        const int ck = cbase - 2048;
#pragma unroll
        for (int m = 0; m < 8; m++)
#pragma unroll
            for (int j = 0; j < 4; j++) {
                size_t ro = (size_t)(rbase + m * 16 + j) * 1024 + ck;
#pragma unroll
                for (int n = 0; n < 4; n++)
                    Ko[ro + n * 16] = f2bf(acc[m][n][j]);
            }
    } else {
#pragma unroll
        for (int m = 0; m < 8; m++)
#pragma unroll
            for (int n = 0; n < 4; n++) {
                int tok = rbase + m * 16;
                int c = cbase + n * 16 - 3072;
                int bb2 = tok >> 11, ss = tok & 2047;
                int h2 = c >> 7, d = c & 127;
                uint2 v;
                v.x = pk2bf(acc[m][n][0], acc[m][n][1]);
                v.y = pk2bf(acc[m][n][2], acc[m][n][3]);
                *(uint2*)(Vo + (size_t)((bb2 * 8 + h2) * 128 + d) * 2048 + ss) = v;
            }
    }
}

// ---------------- m97-style bf16 GEMM, f32 out (Wo GEMM) ----------------
__global__ __launch_bounds__(256) void gemm_wo(const u16* __restrict__ A,
                                               const u16* __restrict__ BT,
                                               float* __restrict__ Of,
                                               int M, int N, int K) {
    __shared__ u16 As[128 * 32];
    __shared__ u16 Bs[128 * 32];
    const int tid = threadIdx.x;
    const int w = tid >> 6, l = tid & 63;
    const int m0 = blockIdx.y * 128, n0 = blockIdx.x * 128;
    const int wr = w >> 1, wc = w & 1;
    const int l15 = l & 15, lh = l >> 4;

    const f32x4 fz = {0.f, 0.f, 0.f, 0.f};
    f32x4 acc[4][4];
#pragma unroll
    for (int m = 0; m < 4; m++)
#pragma unroll
        for (int n = 0; n < 4; n++) acc[m][n] = fz;

    const int rowA = w * 32 + (l >> 2);
    const int colb = (l & 3) * 8;

    for (int k0 = 0; k0 < K; k0 += 32) {
        __syncthreads();
#pragma unroll
        for (int c = 0; c < 2; c++) {
            gload_lds16(A  + (size_t)(m0 + rowA + c * 16) * K + k0 + colb,
                        &As[w * 1024 + c * 512]);
            gload_lds16(BT + (size_t)(n0 + rowA + c * 16) * K + k0 + colb,
                        &Bs[w * 1024 + c * 512]);
        }
        __syncthreads();
        short8 af[4], bfr[4];
#pragma unroll
        for (int m = 0; m < 4; m++)
            af[m] = *(const short8*)&As[(wr * 64 + m * 16 + l15) * 32 + lh * 8];
#pragma unroll
        for (int n = 0; n < 4; n++)
            bfr[n] = *(const short8*)&Bs[(wc * 64 + n * 16 + l15) * 32 + lh * 8];
#pragma unroll
        for (int m = 0; m < 4; m++)
#pragma unroll
            for (int n = 0; n < 4; n++)
                acc[m][n] = mfma16(af[m], bfr[n], acc[m][n]);
    }

    const int rbase = m0 + wr * 64 + lh * 4;
    const int cbase = n0 + wc * 64 + l15;
#pragma unroll
    for (int m = 0; m < 4; m++)
#pragma unroll
        for (int j = 0; j < 4; j++) {
            size_t ro = (size_t)(rbase + m * 16 + j) * N + cbase;
#pragma unroll
            for (int n = 0; n < 4; n++)
                Of[ro + n * 16] = acc[m][n][j];
        }
}

// ---------------- flash attention (non-causal, GQA) ----------------
// grid (16 qtiles of 128 rows, 32 b*h); block 256 = 4 waves; wave owns 32 q rows
// (2 q-groups sharing every K/V fragment read -> 1.6x less LDS traffic).
// K/V double-buffered via global_load_lds w/ pre-swizzled source; 1 barrier/tile.
// exp2-domain softmax (Q pre-scaled by log2e/sqrt(128)); defer-max THR=8;
// lane-local lsum, reduced once in epilogue.
__global__ __launch_bounds__(256, 2) void attn_kernel(const u16* __restrict__ Q,
                                                      const u16* __restrict__ Kg,
                                                      const u16* __restrict__ Vg,
                                                      u16* __restrict__ O) {
    __shared__ __align__(16) u16 Ks[2][8192];  // [buf][key 64][128] swizzled
    __shared__ __align__(16) u16 Vs[2][8192];  // [buf][d 128][64]  swizzled (V^T)
    __shared__ __align__(16) u16 Ps[4][2048];  // per-wave P [q32][k64] swizzled
    const int tid = threadIdx.x;
    const int w = tid >> 6, l = tid & 63;
    const int qt = blockIdx.x, bh = blockIdx.y;
    const int b = bh >> 4, h = bh & 15, h2 = h >> 1;
    const int l15 = l & 15, lh = l >> 4;

    char* KsB = (char*)&Ks[0][0];
    char* VsB = (char*)&Vs[0][0];
    char* PsB = (char*)&Ps[w][0];

    // staging: 256 threads stage K tile (16KB) + V tile (16KB) in 4 chunks each
    const char* Kbase = (const char*)Kg + (size_t)b * 2048 * 2048 + h2 * 256;
    const char* Vbase = (const char*)Vg + (size_t)(b * 8 + h2) * 128 * 4096;
    int krow[4], kcol[4], vrow[4], vcol[4];
#pragma unroll
    for (int c = 0; c < 4; c++) {
        int X = c * 4096 + tid * 16;
        krow[c] = X >> 8; kcol[c] = (X & 255) ^ ((krow[c] & 7) << 4);
        vrow[c] = X >> 7; vcol[c] = (X & 127) ^ ((vrow[c] & 7) << 4);
    }

#define STAGE(t, pb) do {                                               \
        const char* Kt = Kbase + (size_t)(t) * 131072;                  \
        const char* Vt = Vbase + (t) * 128;                             \
        char* kd = KsB + (pb) * 16384 + tid * 16;                       \
        char* vd = VsB + (pb) * 16384 + tid * 16;                       \
        _Pragma("unroll")                                               \
        for (int c = 0; c < 4; c++) {                                   \
            gload_lds16(Kt + krow[c] * 2048 + kcol[c], kd + c * 4096);  \
            gload_lds16(Vt + (size_t)vrow[c] * 4096 + vcol[c], vd + c * 4096); \
        }                                                               \
    } while (0)

    // Q fragments for both q-groups (rows w*32 + g*16 + l15)
    short8 qf0[4], qf1[4];
    {
        const u16* qp = Q + ((size_t)(b * 2048 + qt * 128 + w * 32 + l15)) * 2048
                          + h * 128 + lh * 8;
#pragma unroll
        for (int ks = 0; ks < 4; ks++) {
            qf0[ks] = *(const short8*)(qp + ks * 32);
            qf1[ks] = *(const short8*)(qp + 16 * 2048 + ks * 32);
        }
    }

    const f32x4 fz = {0.f, 0.f, 0.f, 0.f};
    f32x4 o0[8], o1[8];
#pragma unroll
    for (int n = 0; n < 8; n++) { o0[n] = fz; o1[n] = fz; }
    float mrow0[4] = {-1e30f, -1e30f, -1e30f, -1e30f};
    float mrow1[4] = {-1e30f, -1e30f, -1e30f, -1e30f};
    float lsum0[4] = {0.f, 0.f, 0.f, 0.f};
    float lsum1[4] = {0.f, 0.f, 0.f, 0.f};

    STAGE(0, 0);

    for (int t = 0; t < 32; t++) {
        __syncthreads();                 // drains vmcnt(0): stage(t) landed
        const int pb = t & 1;
        if (t < 31) STAGE(t + 1, pb ^ 1);
        const char* kc = KsB + pb * 16384;
        const char* vc = VsB + pb * 16384;
        const int swz = (l15 & 7) << 4;

        // S = Q.K^T for both q-groups; K frags read ONCE
        f32x4 s0[4], s1[4];
#pragma unroll
        for (int ct = 0; ct < 4; ct++) {
            s0[ct] = fz; s1[ct] = fz;
#pragma unroll
            for (int ks = 0; ks < 4; ks++) {
                short8 kf = *(const short8*)(kc + ((ct * 16 + l15) << 8)
                                                + ((ks * 64 + lh * 16) ^ swz));
                s0[ct] = mfma16(qf0[ks], kf, s0[ct]);
                s1[ct] = mfma16(qf1[ks], kf, s1[ct]);
            }
        }

        // defer-max online softmax, both groups
        float pl0[4], pl1[4];
#pragma unroll
        for (int r = 0; r < 4; r++) {
            pl0[r] = fmaxf(fmaxf(s0[0][r], s0[1][r]), fmaxf(s0[2][r], s0[3][r]));
            pl1[r] = fmaxf(fmaxf(s1[0][r], s1[1][r]), fmaxf(s1[2][r], s1[3][r]));
        }
        bool grow = false;
#pragma unroll
        for (int r = 0; r < 4; r++)
            grow = grow || (pl0[r] > mrow0[r] + 8.f) || (pl1[r] > mrow1[r] + 8.f);
        if (__any(grow)) {
#pragma unroll
            for (int r = 0; r < 4; r++) {
                float mx = pl0[r];
                mx = fmaxf(mx, __shfl_xor(mx, 1));
                mx = fmaxf(mx, __shfl_xor(mx, 2));
                mx = fmaxf(mx, __shfl_xor(mx, 4));
                mx = fmaxf(mx, __shfl_xor(mx, 8));
                float mnew = fmaxf(mrow0[r], mx);
                float fsc = exp2f(mrow0[r] - mnew);
                mrow0[r] = mnew;
                lsum0[r] *= fsc;
#pragma unroll
                for (int n = 0; n < 8; n++) o0[n][r] *= fsc;
            }
#pragma unroll
            for (int r = 0; r < 4; r++) {
                float mx = pl1[r];
                mx = fmaxf(mx, __shfl_xor(mx, 1));
                mx = fmaxf(mx, __shfl_xor(mx, 2));
                mx = fmaxf(mx, __shfl_xor(mx, 4));
                mx = fmaxf(mx, __shfl_xor(mx, 8));
                float mnew = fmaxf(mrow1[r], mx);
                float fsc = exp2f(mrow1[r] - mnew);
                mrow1[r] = mnew;
                lsum1[r] *= fsc;
#pragma unroll
                for (int n = 0; n < 8; n++) o1[n][r] *= fsc;
            }
        }
        const int cb2 = l15 << 1;
#pragma unroll
        for (int r = 0; r < 4; r++) {
            float p0 = exp2f(s0[0][r] - mrow0[r]);
            float p1 = exp2f(s0[1][r] - mrow0[r]);
            float p2 = exp2f(s0[2][r] - mrow0[r]);
            float p3 = exp2f(s0[3][r] - mrow0[r]);
            lsum0[r] += (p0 + p1) + (p2 + p3);
            const int rw = lh * 4 + r;
            const int rb = rw << 7;
            const int sw2 = (rw & 7) << 4;
            *(u16*)(PsB + (rb + (( 0 + cb2) ^ sw2))) =
                (u16)((__float_as_uint(p0) + 0x8000u) >> 16);
            *(u16*)(PsB + (rb + ((32 + cb2) ^ sw2))) =
                (u16)((__float_as_uint(p1) + 0x8000u) >> 16);
            *(u16*)(PsB + (rb + ((64 + cb2) ^ sw2))) =
                (u16)((__float_as_uint(p2) + 0x8000u) >> 16);
            *(u16*)(PsB + (rb + ((96 + cb2) ^ sw2))) =
                (u16)((__float_as_uint(p3) + 0x8000u) >> 16);
        }
#pragma unroll
        for (int r = 0; r < 4; r++) {
            float p0 = exp2f(s1[0][r] - mrow1[r]);
            float p1 = exp2f(s1[1][r] - mrow1[r]);
            float p2 = exp2f(s1[2][r] - mrow1[r]);
            float p3 = exp2f(s1[3][r] - mrow1[r]);
            lsum1[r] += (p0 + p1) + (p2 + p3);
            const int rw = 16 + lh * 4 + r;
            const int rb = rw << 7;
            const int sw2 = (rw & 7) << 4;
            *(u16*)(PsB + (rb + (( 0 + cb2) ^ sw2))) =
                (u16)((__float_as_uint(p0) + 0x8000u) >> 16);
            *(u16*)(PsB + (rb + ((32 + cb2) ^ sw2))) =
                (u16)((__float_as_uint(p1) + 0x8000u) >> 16);
            *(u16*)(PsB + (rb + ((64 + cb2) ^ sw2))) =
                (u16)((__float_as_uint(p2) + 0x8000u) >> 16);
            *(u16*)(PsB + (rb + ((96 + cb2) ^ sw2))) =
                (u16)((__float_as_uint(p3) + 0x8000u) >> 16);
        }

        // PV for both groups; V frags read ONCE
#pragma unroll
        for (int ks2 = 0; ks2 < 2; ks2++) {
            short8 pf0 = *(const short8*)(PsB + ((l15 << 7)
                                + ((ks2 * 64 + lh * 16) ^ swz)));
            short8 pf1 = *(const short8*)(PsB + (((16 + l15) << 7)
                                + ((ks2 * 64 + lh * 16) ^ swz)));
#pragma unroll
            for (int n = 0; n < 8; n++) {
                short8 vf = *(const short8*)(vc + (((n * 16 + l15) << 7)
                                                  + ((ks2 * 64 + lh * 16) ^ swz)));
                o0[n] = mfma16(pf0, vf, o0[n]);
                o1[n] = mfma16(pf1, vf, o1[n]);
            }
        }
    }

    const size_t ob0 = ((size_t)(b * 2048 + qt * 128 + w * 32 + lh * 4)) * 2048
                       + h * 128 + l15;
#pragma unroll
    for (int r = 0; r < 4; r++) {
        float ls = lsum0[r];
        ls += __shfl_xor(ls, 1);
        ls += __shfl_xor(ls, 2);
        ls += __shfl_xor(ls, 4);
        ls += __shfl_xor(ls, 8);
        float li = 1.0f / ls;
#pragma unroll
        for (int n = 0; n < 8; n++)
            O[ob0 + (size_t)r * 2048 + n * 16] = f2bf(o0[n][r] * li);
    }
    const size_t ob1 = ob0 + (size_t)16 * 2048;
#pragma unroll
    for (int r = 0; r < 4; r++) {
        float ls = lsum1[r];
        ls += __shfl_xor(ls, 1);
        ls += __shfl_xor(ls, 2);
        ls += __shfl_xor(ls, 4);
        ls += __shfl_xor(ls, 8);
        float li = 1.0f / ls;
#pragma unroll
        for (int n = 0; n < 8; n++)
            O[ob1 + (size_t)r * 2048 + n * 16] = f2bf(o1[n][r] * li);
    }
#undef STAGE
}

// ---------------- launch ----------------
extern "C" void kernel_launch(void* const* d_in, const int* in_sizes, int n_in,
                              void* d_out, int out_size, void* d_ws, size_t ws_size,
                              hipStream_t stream) {
    const float* x  = (const float*)d_in[0];
    const float* Wq = (const float*)d_in[1];
    const float* Wk = (const float*)d_in[2];
    const float* Wv = (const float*)d_in[3];
    const float* Wo = (const float*)d_in[4];
    const float* fc = (const float*)d_in[5];
    const float* fs = (const float*)d_in[6];
    float* out = (float*)d_out;

    uint8_t* ws = (uint8_t*)d_ws;
    u16* xb   = (u16*)(ws + 0);          // 16.8 MB  (aliased as attn_out later)
    u16* wqkv = (u16*)(ws + 16777216);   // 16.8 MB: wqT | wkT | wvT contiguous
    u16* wqT  = (u16*)(ws + 16777216);
    u16* wkT  = (u16*)(ws + 25165824);
    u16* wvT  = (u16*)(ws + 29360128);
    u16* woT  = (u16*)(ws + 33554432);   // 8.4 MB
    u16* qb   = (u16*)(ws + 41943040);   // 16.8 MB
    u16* kb   = (u16*)(ws + 58720256);   // 8.4 MB
    u16* vT   = (u16*)(ws + 67108864);   // 8.4 MB   total 75.5 MB
    u16* ao   = xb;                      // alias: x_bf16 dead after QKV gemm

    cvt_x<<<dim3(8192), dim3(256), 0, stream>>>(x, xb, 2097152);
    transpose_cvt4<<<dim3(32, 32, 4), dim3(256), 0, stream>>>(Wq, Wk, Wv, Wo,
                                                              wqT, wkT, wvT, woT);

    gemm_qkv8<<<dim3(256), dim3(512), 0, stream>>>(xb, wqkv, qb, kb, vT);

    // Q carries (1/sqrt(128)) * log2(e) so softmax runs in exp2 domain
    rope_kernel<<<dim3(16384), dim3(256), 0, stream>>>(qb, fc, fs, 16, 10, 4194304,
                                                       0.12751742987f);
    rope_kernel<<<dim3(8192),  dim3(256), 0, stream>>>(kb, fc, fs, 8, 9, 2097152, 1.0f);

    attn_kernel<<<dim3(16, 32), dim3(256), 0, stream>>>(qb, kb, vT, ao);

    gemm_wo<<<dim3(16, 32), dim3(256), 0, stream>>>(ao, woT, out, 4096, 2048, 2048);
}